// Round 3
// baseline (409.342 us; speedup 1.0000x reference)
//
#include <hip/hip_runtime.h>

// ============================================================================
// theta is batch-uniform => M = U^dag Z0 U is fixed. Embedded state is a
// product state: <psi|M|psi> = sum over {I,Z,Y}^8 strings of
// alpha_P * prod_w m_w,  m_w(I)=1, m_w(Z)=cos x_w, m_w(Y)=-sin x_w.
//
// k_alpha (1 block): sparse Heisenberg propagation of Z0 through the fixed
//   circuit using numeric PTMs + CNOT conjugation table (both verified in
//   round 2). Writes alpha[243*28] (padded) to ws.
// k_main: per-thread factorized 6561-term contraction; alpha read directly
//   from global with wave-uniform indices (scalar-cache path, no LDS).
// ============================================================================

struct cpx { float re, im; };
__device__ __forceinline__ cpx cmul(cpx a, cpx b) {
    return {a.re * b.re - a.im * b.im, a.re * b.im + a.im * b.re};
}

__device__ __forceinline__ void get_pauli(int a, cpx P[2][2]) {
    cpx z{0.f, 0.f};
    P[0][0] = z; P[0][1] = z; P[1][0] = z; P[1][1] = z;
    switch (a) {
        case 0: P[0][0] = {1.f, 0.f}; P[1][1] = {1.f, 0.f}; break;   // I
        case 1: P[0][1] = {1.f, 0.f}; P[1][0] = {1.f, 0.f}; break;   // X
        case 2: P[0][1] = {0.f, -1.f}; P[1][0] = {0.f, 1.f}; break;  // Y
        case 3: P[0][0] = {1.f, 0.f}; P[1][1] = {-1.f, 0.f}; break;  // Z
    }
}

// ws float layout: ALPHA[243*28] | (scratch) MIDS ints | MIDC floats
#define OFF_ALPHA 0
#define OFF_MIDS  8192
#define OFF_MIDC  16384
#define WS_FLOATS_NEEDED (16384 + 6561)

// Conjugate Pauli string `cur` by ring of CNOT(w, w+r), w=0..7 (applied in
// circuit order) -- identical index math to round-2's verified k_ring.
__device__ __forceinline__ int ring_conj(int cur, int r, const int* CIDX,
                                         const float* CSGN, float& sg) {
    for (int w = 7; w >= 0; --w) {
        const int tw = (w + r) & 7;
        const int pc = (cur >> (2 * w)) & 3;
        const int pt = (cur >> (2 * tw)) & 3;
        const int q = pc * 4 + pt;
        const int nq = CIDX[q];
        sg *= CSGN[q];
        cur = (cur & ~((3 << (2 * w)) | (3 << (2 * tw))))
            | ((nq >> 2) << (2 * w)) | ((nq & 3) << (2 * tw));
    }
    return cur;
}

// ---------------------------------------------------------------------------
// Single-launch prepass.
// ---------------------------------------------------------------------------
__global__ __launch_bounds__(256) void k_alpha(const float* __restrict__ theta,
                                               float* __restrict__ ws) {
    __shared__ float TR[256];      // 16 gates x 4x4 PTM
    __shared__ float CSGN[16];
    __shared__ int   CIDX[16];
    __shared__ float al[243 * 28];
    __shared__ int   S1str, S1k, S1n;
    __shared__ float S1sgn;
    __shared__ int   S1w[8], S1l[8];

    int*   MIDS = (int*)(ws + OFF_MIDS);
    float* MIDC = ws + OFF_MIDC;

    const int tid = threadIdx.x;
    for (int i = tid; i < 243 * 28; i += 256) al[i] = 0.f;

    // ---- tables (verified round 2) ----
    if (tid < 16) {
        const int l = tid >> 3, w = tid & 7;
        const float phi = theta[(l * 8 + w) * 3 + 0];
        const float th  = theta[(l * 8 + w) * 3 + 1];
        const float om  = theta[(l * 8 + w) * 3 + 2];
        const float c = cosf(0.5f * th), s = sinf(0.5f * th);
        const float ps = 0.5f * (phi + om), ms = 0.5f * (phi - om);
        cpx G[2][2];
        G[0][0] = {c * cosf(ps), -c * sinf(ps)};
        G[0][1] = {-s * cosf(ms), -s * sinf(ms)};
        G[1][0] = {s * cosf(ms), -s * sinf(ms)};
        G[1][1] = {c * cosf(ps), c * sinf(ps)};
        for (int a = 0; a < 4; ++a) {
            cpx Pa[2][2]; get_pauli(a, Pa);
            cpx M1[2][2];
            for (int i = 0; i < 2; ++i)
                for (int j = 0; j < 2; ++j) {
                    cpx acc{0.f, 0.f};
                    for (int k = 0; k < 2; ++k) {
                        cpx t = cmul(Pa[i][k], G[k][j]);
                        acc.re += t.re; acc.im += t.im;
                    }
                    M1[i][j] = acc;
                }
            cpx H[2][2];
            for (int i = 0; i < 2; ++i)
                for (int j = 0; j < 2; ++j) {
                    cpx acc{0.f, 0.f};
                    for (int k = 0; k < 2; ++k) {
                        cpx gc{G[k][i].re, -G[k][i].im};
                        cpx t = cmul(gc, M1[k][j]);
                        acc.re += t.re; acc.im += t.im;
                    }
                    H[i][j] = acc;
                }
            for (int b = 0; b < 4; ++b) {
                cpx Pb[2][2]; get_pauli(b, Pb);
                float tr = 0.f;
                for (int i = 0; i < 2; ++i)
                    for (int j = 0; j < 2; ++j)
                        tr += Pb[i][j].re * H[j][i].re - Pb[i][j].im * H[j][i].im;
                TR[tid * 16 + a * 4 + b] = 0.5f * tr;
            }
        }
    }
    if (tid == 16) {
        const int perm[4] = {0, 1, 3, 2};
        for (int pc = 0; pc < 4; ++pc)
            for (int pt = 0; pt < 4; ++pt) {
                cpx Pc[2][2], Pt[2][2];
                get_pauli(pc, Pc); get_pauli(pt, Pt);
                cpx S[4][4];
                for (int i = 0; i < 2; ++i)
                    for (int j = 0; j < 2; ++j)
                        for (int k = 0; k < 2; ++k)
                            for (int l2 = 0; l2 < 2; ++l2)
                                S[2 * i + j][2 * k + l2] = cmul(Pc[i][k], Pt[j][l2]);
                cpx R[4][4];
                for (int r = 0; r < 4; ++r)
                    for (int c2 = 0; c2 < 4; ++c2)
                        R[r][c2] = S[perm[r]][perm[c2]];
                int bidx = 0; float bsgn = 1.f;
                for (int a = 0; a < 4; ++a)
                    for (int b2 = 0; b2 < 4; ++b2) {
                        cpx Pa[2][2], Pb[2][2];
                        get_pauli(a, Pa); get_pauli(b2, Pb);
                        float ov = 0.f;
                        for (int r = 0; r < 4; ++r)
                            for (int c2 = 0; c2 < 4; ++c2) {
                                cpx K = cmul(Pa[r >> 1][c2 >> 1], Pb[r & 1][c2 & 1]);
                                ov += K.re * R[r][c2].re + K.im * R[r][c2].im;
                            }
                        ov *= 0.25f;
                        if (ov > 0.5f) { bidx = a * 4 + b2; bsgn = 1.f; }
                        else if (ov < -0.5f) { bidx = a * 4 + b2; bsgn = -1.f; }
                    }
                CIDX[pc * 4 + pt] = bidx;
                CSGN[pc * 4 + pt] = bsgn;
            }
    }
    __syncthreads();

    // ---- stage 0: S1 = Ring2^dag Z0 Ring2 (single string) ----
    if (tid == 0) {
        float sg = 1.f;
        int cur = ring_conj(3 /* Z on wire 0 */, 2, CIDX, CSGN, sg);
        int k = 0;
        for (int w = 0; w < 8; ++w) {
            const int ltr = (cur >> (2 * w)) & 3;
            if (ltr != 0) { S1w[k] = w; S1l[k] = ltr; ++k; }
        }
        int n = 1;
        for (int i = 0; i < k; ++i) n *= 3;
        S1str = cur; S1sgn = sg; S1k = k; S1n = n;
    }
    __syncthreads();

    const int k1 = S1k, n1 = S1n;

    // ---- stage 1: Rot layer-1 conj expansion (3^k1 terms) ----
    for (int t = tid; t < n1; t += 256) {
        float c = S1sgn;
        int s = 0;
        int tt = t;
        for (int i = 0; i < k1; ++i) {
            const int bl = tt % 3 + 1;  // X=1,Y=2,Z=3
            tt /= 3;
            c *= TR[(8 + S1w[i]) * 16 + S1l[i] * 4 + bl];
            s |= bl << (2 * S1w[i]);
        }
        MIDS[t] = s;
        MIDC[t] = c;
    }
    __syncthreads();

    // ---- stage 2: Ring1 conj (permutation + sign) ----
    for (int t = tid; t < n1; t += 256) {
        float sg = 1.f;
        const int s = ring_conj(MIDS[t], 1, CIDX, CSGN, sg);
        MIDS[t] = s;
        MIDC[t] *= sg;
    }
    __syncthreads();

    // ---- stage 3: Rot layer-0 conj, drop X (zero expectation), accumulate ----
    const int P3[8] = {2187, 729, 243, 81, 27, 9, 3, 1};  // 3^(7-w)
    for (int e = tid; e < n1; e += 256) {
        const int s = MIDS[e];
        const float c = MIDC[e];
        int sw[8], sl[8], k = 0;
        for (int w = 0; w < 8; ++w) {
            const int ltr = (s >> (2 * w)) & 3;
            if (ltr != 0) { sw[k] = w; sl[k] = ltr; ++k; }
        }
        for (int t = 0; t < (1 << k); ++t) {
            float cc = c;
            int t3 = 0;
            for (int i = 0; i < k; ++i) {
                const int bit = (t >> i) & 1;
                const int b = bit ? 2 : 3;   // Y : Z
                const int d = bit ? 2 : 1;   // base-3 digit: Z=1, Y=2
                cc *= TR[sw[i] * 16 + sl[i] * 4 + b];
                t3 += d * P3[sw[i]];
            }
            atomicAdd(&al[(t3 / 27) * 28 + (t3 % 27)], cc);
        }
    }
    __syncthreads();

    // ---- write alpha (padded 243x28) ----
    for (int i = tid; i < 243 * 28; i += 256) ws[OFF_ALPHA + i] = al[i];
}

// ---------------------------------------------------------------------------
// Main contraction: alpha read straight from global with wave-uniform
// indices (scalar path). No LDS, no barriers.
// ---------------------------------------------------------------------------
__global__ __launch_bounds__(256) void k_main(const float* __restrict__ x,
                                              const float* __restrict__ Aq,
                                              float* __restrict__ out, int batch) {
    const int b = blockIdx.x * 256 + threadIdx.x;
    if (b >= batch) return;

    const float4* xp = (const float4*)(x + (size_t)b * 8);
    const float4 xa = xp[0], xb = xp[1];
    const float xs[8] = {xa.x, xa.y, xa.z, xa.w, xb.x, xb.y, xb.z, xb.w};
    float cw[8], msw[8];
#pragma unroll
    for (int w = 0; w < 8; ++w) {
        float sv, cv;
        __sincosf(xs[w], &sv, &cv);
        cw[w] = cv;
        msw[w] = -sv;
    }
    float f567[28];
    {
        const float F5[3] = {1.f, cw[5], msw[5]};
        const float F6[3] = {1.f, cw[6], msw[6]};
        const float F7[3] = {1.f, cw[7], msw[7]};
        int j = 0;
#pragma unroll
        for (int a = 0; a < 3; ++a)
#pragma unroll
            for (int b2 = 0; b2 < 3; ++b2)
#pragma unroll
                for (int c2 = 0; c2 < 3; ++c2) f567[j++] = F5[a] * F6[b2] * F7[c2];
        f567[27] = 0.f;
    }

    float acc = 0.f;
    int base = 0;
    for (int k0 = 0; k0 < 3; ++k0) {
        const float p0 = (k0 == 0) ? 1.f : ((k0 == 1) ? cw[0] : msw[0]);
        for (int k1 = 0; k1 < 3; ++k1) {
            const float p1 = p0 * ((k1 == 0) ? 1.f : ((k1 == 1) ? cw[1] : msw[1]));
            for (int k2 = 0; k2 < 3; ++k2) {
                const float p2 = p1 * ((k2 == 0) ? 1.f : ((k2 == 1) ? cw[2] : msw[2]));
#pragma unroll
                for (int k3 = 0; k3 < 3; ++k3) {
                    const float p3 = p2 * ((k3 == 0) ? 1.f : ((k3 == 1) ? cw[3] : msw[3]));
#pragma unroll
                    for (int k4 = 0; k4 < 3; ++k4) {
                        const float p4 = p3 * ((k4 == 0) ? 1.f : ((k4 == 1) ? cw[4] : msw[4]));
                        const float* Ap = Aq + base;  // wave-uniform address
                        float t0 = 0.f, t1 = 0.f, t2 = 0.f, t3v = 0.f;
#pragma unroll
                        for (int j = 0; j < 28; j += 4) {
                            t0  = fmaf(Ap[j + 0], f567[j + 0], t0);
                            t1  = fmaf(Ap[j + 1], f567[j + 1], t1);
                            t2  = fmaf(Ap[j + 2], f567[j + 2], t2);
                            t3v = fmaf(Ap[j + 3], f567[j + 3], t3v);
                        }
                        acc = fmaf((t0 + t1) + (t2 + t3v), p4, acc);
                        base += 28;
                    }
                }
            }
        }
    }
    out[b] = (acc + 1.f) * 0.5f;
}

// ============================================================================
// Fallback: round-1 direct statevector simulator (used if ws too small).
// ============================================================================
struct c32 { float x, y; };

__device__ __forceinline__ c32 shfl_xor_c(c32 v, int mask) {
    c32 r;
    r.x = __shfl_xor(v.x, mask, 64);
    r.y = __shfl_xor(v.y, mask, 64);
    return r;
}
__device__ __forceinline__ c32 cmadd2(c32 ga, c32 a, c32 gp, c32 p) {
    c32 n;
    n.x = ga.x * a.x - ga.y * a.y + gp.x * p.x - gp.y * p.y;
    n.y = ga.x * a.y + ga.y * a.x + gp.x * p.y + gp.y * p.x;
    return n;
}
__device__ __forceinline__ c32 rx_mix(float c, float s, c32 a, c32 p) {
    c32 n;
    n.x = c * a.x + s * p.y;
    n.y = c * a.y - s * p.x;
    return n;
}
__device__ __forceinline__ void apply_rx(c32 st[4], int lane, int bb, float c, float s) {
    if (bb < 6) {
#pragma unroll
        for (int r = 0; r < 4; ++r) {
            c32 p = shfl_xor_c(st[r], 1 << bb);
            st[r] = rx_mix(c, s, st[r], p);
        }
    } else if (bb == 6) {
        c32 n0 = rx_mix(c, s, st[0], st[1]);
        c32 n1 = rx_mix(c, s, st[1], st[0]);
        c32 n2 = rx_mix(c, s, st[2], st[3]);
        c32 n3 = rx_mix(c, s, st[3], st[2]);
        st[0] = n0; st[1] = n1; st[2] = n2; st[3] = n3;
    } else {
        c32 n0 = rx_mix(c, s, st[0], st[2]);
        c32 n2 = rx_mix(c, s, st[2], st[0]);
        c32 n1 = rx_mix(c, s, st[1], st[3]);
        c32 n3 = rx_mix(c, s, st[3], st[1]);
        st[0] = n0; st[1] = n1; st[2] = n2; st[3] = n3;
    }
}
__device__ __forceinline__ void apply_rot(c32 st[4], int lane, int bb,
                                          c32 g00, c32 g01, c32 g10, c32 g11) {
    if (bb < 6) {
#pragma unroll
        for (int r = 0; r < 4; ++r) {
            c32 p = shfl_xor_c(st[r], 1 << bb);
            bool hi = (lane >> bb) & 1;
            c32 ga, gp;
            ga.x = hi ? g11.x : g00.x;
            ga.y = hi ? g11.y : g00.y;
            gp.x = hi ? g10.x : g01.x;
            gp.y = hi ? g10.y : g01.y;
            st[r] = cmadd2(ga, st[r], gp, p);
        }
    } else if (bb == 6) {
        c32 n0 = cmadd2(g00, st[0], g01, st[1]);
        c32 n1 = cmadd2(g10, st[0], g11, st[1]);
        c32 n2 = cmadd2(g00, st[2], g01, st[3]);
        c32 n3 = cmadd2(g10, st[2], g11, st[3]);
        st[0] = n0; st[1] = n1; st[2] = n2; st[3] = n3;
    } else {
        c32 n0 = cmadd2(g00, st[0], g01, st[2]);
        c32 n2 = cmadd2(g10, st[0], g11, st[2]);
        c32 n1 = cmadd2(g00, st[1], g01, st[3]);
        c32 n3 = cmadd2(g10, st[1], g11, st[3]);
        st[0] = n0; st[1] = n1; st[2] = n2; st[3] = n3;
    }
}
__device__ __forceinline__ void cswap(bool c, c32& a, c32& b) {
    c32 t = a;
    a.x = c ? b.x : a.x; a.y = c ? b.y : a.y;
    b.x = c ? t.x : b.x; b.y = c ? t.y : b.y;
}
__device__ __forceinline__ void apply_cnot(c32 st[4], int lane, int bc, int bt) {
    if (bt < 6) {
        if (bc < 6) {
            bool ctrl = (lane >> bc) & 1;
#pragma unroll
            for (int r = 0; r < 4; ++r) {
                c32 p = shfl_xor_c(st[r], 1 << bt);
                st[r].x = ctrl ? p.x : st[r].x;
                st[r].y = ctrl ? p.y : st[r].y;
            }
        } else {
#pragma unroll
            for (int r = 0; r < 4; ++r) {
                if ((r >> (bc - 6)) & 1) st[r] = shfl_xor_c(st[r], 1 << bt);
            }
        }
    } else {
        if (bc < 6) {
            bool ctrl = (lane >> bc) & 1;
            if (bt == 6) { cswap(ctrl, st[0], st[1]); cswap(ctrl, st[2], st[3]); }
            else         { cswap(ctrl, st[0], st[2]); cswap(ctrl, st[1], st[3]); }
        } else {
            if (bc == 7 && bt == 6) { c32 t = st[2]; st[2] = st[3]; st[3] = t; }
            else if (bc == 6 && bt == 7) { c32 t = st[1]; st[1] = st[3]; st[3] = t; }
        }
    }
}
__global__ __launch_bounds__(256) void qsim_kernel(const float* __restrict__ x,
                                                   const float* __restrict__ theta,
                                                   float* __restrict__ out,
                                                   int batch) {
    __shared__ float rot[2 * 8 * 8];
    const int t = threadIdx.x;
    if (t < 16) {
        const int l = t >> 3, w = t & 7;
        const float phi = theta[(l * 8 + w) * 3 + 0];
        const float th  = theta[(l * 8 + w) * 3 + 1];
        const float om  = theta[(l * 8 + w) * 3 + 2];
        const float c = cosf(0.5f * th), s = sinf(0.5f * th);
        const float p = 0.5f * (phi + om), m = 0.5f * (phi - om);
        float* g = &rot[t * 8];
        g[0] = c * cosf(p);  g[1] = -c * sinf(p);
        g[2] = -s * cosf(m); g[3] = -s * sinf(m);
        g[4] = s * cosf(m);  g[5] = -s * sinf(m);
        g[6] = c * cosf(p);  g[7] = c * sinf(p);
    }
    __syncthreads();
    const int lane = t & 63;
    const int b = blockIdx.x * 4 + (t >> 6);
    if (b >= batch) return;
    float c8 = 0.f, s8 = 0.f;
    if (lane < 8) {
        const float xv = 0.5f * x[b * 8 + lane];
        c8 = cosf(xv); s8 = sinf(xv);
    }
    c32 st[4];
#pragma unroll
    for (int r = 0; r < 4; ++r) { st[r].x = 0.f; st[r].y = 0.f; }
    if (lane == 0) st[0].x = 1.f;
#pragma unroll
    for (int w = 0; w < 8; ++w) {
        const float c = __shfl(c8, w, 64);
        const float s = __shfl(s8, w, 64);
        apply_rx(st, lane, 7 - w, c, s);
    }
#pragma unroll
    for (int l = 0; l < 2; ++l) {
#pragma unroll
        for (int w = 0; w < 8; ++w) {
            const float* g = &rot[(l * 8 + w) * 8];
            c32 g00{g[0], g[1]}, g01{g[2], g[3]}, g10{g[4], g[5]}, g11{g[6], g[7]};
            apply_rot(st, lane, 7 - w, g00, g01, g10, g11);
        }
        const int rr = l + 1;
#pragma unroll
        for (int w = 0; w < 8; ++w) apply_cnot(st, lane, 7 - w, 7 - ((w + rr) & 7));
    }
    float v = st[0].x * st[0].x + st[0].y * st[0].y
            + st[1].x * st[1].x + st[1].y * st[1].y
            - st[2].x * st[2].x - st[2].y * st[2].y
            - st[3].x * st[3].x - st[3].y * st[3].y;
#pragma unroll
    for (int off = 32; off > 0; off >>= 1) v += __shfl_xor(v, off, 64);
    if (lane == 0) out[b] = (v + 1.f) * 0.5f;
}

// ============================================================================
extern "C" void kernel_launch(void* const* d_in, const int* in_sizes, int n_in,
                              void* d_out, int out_size, void* d_ws, size_t ws_size,
                              hipStream_t stream) {
    const float* x     = (const float*)d_in[0];
    const float* theta = (const float*)d_in[1];
    float* out = (float*)d_out;
    const int batch = in_sizes[0] / 8;

    if (ws_size >= (size_t)WS_FLOATS_NEEDED * 4 + 256) {
        float* ws = (float*)d_ws;
        k_alpha<<<dim3(1), dim3(256), 0, stream>>>(theta, ws);
        k_main<<<dim3((batch + 255) / 256), dim3(256), 0, stream>>>(
            x, ws + OFF_ALPHA, out, batch);
    } else {
        qsim_kernel<<<dim3((batch + 3) / 4), dim3(256), 0, stream>>>(x, theta, out, batch);
    }
}

// Round 4
// 282.137 us; speedup vs baseline: 1.4509x; 1.4509x over previous
//
#include <hip/hip_runtime.h>

// ============================================================================
// theta is batch-uniform => M = U^dag Z0 U is fixed. Embedded state is a
// product state: <psi|M|psi> = sum over {I,Z,Y}^8 strings of
// alpha_P * prod_w m_w,  m_w(I)=1, m_w(Z)=cos x_w, m_w(Y)=-sin x_w.
//
// k_alpha (1 block): sparse Heisenberg propagation of Z0 (numeric PTMs +
//   CNOT table, math verified rounds 2-3), then a DENSE wire-by-wire PTM
//   transform (ping-pong in ws, no atomics) to produce alpha[243*28].
// k_main2: 3 threads per element (split by k0 across the 3 waves of a
//   192-thread block), factorized contraction, LDS reduce.
// ============================================================================

struct cpx { float re, im; };
__device__ __forceinline__ cpx cmul(cpx a, cpx b) {
    return {a.re * b.re - a.im * b.im, a.re * b.im + a.im * b.re};
}

__device__ __forceinline__ void get_pauli(int a, cpx P[2][2]) {
    cpx z{0.f, 0.f};
    P[0][0] = z; P[0][1] = z; P[1][0] = z; P[1][1] = z;
    switch (a) {
        case 0: P[0][0] = {1.f, 0.f}; P[1][1] = {1.f, 0.f}; break;   // I
        case 1: P[0][1] = {1.f, 0.f}; P[1][0] = {1.f, 0.f}; break;   // X
        case 2: P[0][1] = {0.f, -1.f}; P[1][0] = {0.f, 1.f}; break;  // Y
        case 3: P[0][0] = {1.f, 0.f}; P[1][1] = {-1.f, 0.f}; break;  // Z
    }
}

// ws float layout: ALPHA[243*28] | D0[65536] | D1[49152]
#define OFF_ALPHA 0
#define OFF_D0    8192
#define OFF_D1    (8192 + 65536)
#define WS_FLOATS_NEEDED (8192 + 65536 + 49152)

// Conjugate Pauli string `cur` by ring of CNOT(w, w+r), w=0..7 (circuit order).
__device__ __forceinline__ int ring_conj(int cur, int r, const int* CIDX,
                                         const float* CSGN, float& sg) {
    for (int w = 7; w >= 0; --w) {
        const int tw = (w + r) & 7;
        const int pc = (cur >> (2 * w)) & 3;
        const int pt = (cur >> (2 * tw)) & 3;
        const int q = pc * 4 + pt;
        const int nq = CIDX[q];
        sg *= CSGN[q];
        cur = (cur & ~((3 << (2 * w)) | (3 << (2 * tw))))
            | ((nq >> 2) << (2 * w)) | ((nq & 3) << (2 * tw));
    }
    return cur;
}

// ---------------------------------------------------------------------------
// Single-launch prepass, parallelized.
// ---------------------------------------------------------------------------
__global__ __launch_bounds__(256) void k_alpha(const float* __restrict__ theta,
                                               float* __restrict__ ws) {
    __shared__ float TR[256];      // 16 gates x 4x4 PTM
    __shared__ float CSGN[16];
    __shared__ int   CIDX[16];
    __shared__ int   MIDS[6561];
    __shared__ float MIDC[6561];
    __shared__ int   S1k, S1n;
    __shared__ float S1sgn;
    __shared__ int   S1w[8], S1l[8];

    float* ALPHA = ws + OFF_ALPHA;
    float* D0 = ws + OFF_D0;
    float* D1 = ws + OFF_D1;

    const int tid = threadIdx.x;

    // ---- zero dense buffer + alpha (all threads) ----
    for (int i = tid; i < 65536; i += 256) D0[i] = 0.f;
    for (int i = tid; i < 243 * 28; i += 256) ALPHA[i] = 0.f;

    // ---- PTMs: threads 0-15 (wave 0); CNOT table: threads 64-79 (wave 1) ----
    if (tid < 16) {
        const int l = tid >> 3, w = tid & 7;
        const float phi = theta[(l * 8 + w) * 3 + 0];
        const float th  = theta[(l * 8 + w) * 3 + 1];
        const float om  = theta[(l * 8 + w) * 3 + 2];
        const float c = cosf(0.5f * th), s = sinf(0.5f * th);
        const float ps = 0.5f * (phi + om), ms = 0.5f * (phi - om);
        cpx G[2][2];
        G[0][0] = {c * cosf(ps), -c * sinf(ps)};
        G[0][1] = {-s * cosf(ms), -s * sinf(ms)};
        G[1][0] = {s * cosf(ms), -s * sinf(ms)};
        G[1][1] = {c * cosf(ps), c * sinf(ps)};
        for (int a = 0; a < 4; ++a) {
            cpx Pa[2][2]; get_pauli(a, Pa);
            cpx M1[2][2];
            for (int i = 0; i < 2; ++i)
                for (int j = 0; j < 2; ++j) {
                    cpx acc{0.f, 0.f};
                    for (int k = 0; k < 2; ++k) {
                        cpx t = cmul(Pa[i][k], G[k][j]);
                        acc.re += t.re; acc.im += t.im;
                    }
                    M1[i][j] = acc;
                }
            cpx H[2][2];
            for (int i = 0; i < 2; ++i)
                for (int j = 0; j < 2; ++j) {
                    cpx acc{0.f, 0.f};
                    for (int k = 0; k < 2; ++k) {
                        cpx gc{G[k][i].re, -G[k][i].im};
                        cpx t = cmul(gc, M1[k][j]);
                        acc.re += t.re; acc.im += t.im;
                    }
                    H[i][j] = acc;
                }
            for (int b = 0; b < 4; ++b) {
                cpx Pb[2][2]; get_pauli(b, Pb);
                float tr = 0.f;
                for (int i = 0; i < 2; ++i)
                    for (int j = 0; j < 2; ++j)
                        tr += Pb[i][j].re * H[j][i].re - Pb[i][j].im * H[j][i].im;
                TR[tid * 16 + a * 4 + b] = 0.5f * tr;
            }
        }
    }
    if (tid >= 64 && tid < 80) {
        const int pr = tid - 64;
        const int pc = pr >> 2, pt = pr & 3;
        const int perm[4] = {0, 1, 3, 2};
        cpx Pc[2][2], Pt[2][2];
        get_pauli(pc, Pc); get_pauli(pt, Pt);
        cpx S[4][4];
        for (int i = 0; i < 2; ++i)
            for (int j = 0; j < 2; ++j)
                for (int k = 0; k < 2; ++k)
                    for (int l2 = 0; l2 < 2; ++l2)
                        S[2 * i + j][2 * k + l2] = cmul(Pc[i][k], Pt[j][l2]);
        cpx R[4][4];
        for (int r = 0; r < 4; ++r)
            for (int c2 = 0; c2 < 4; ++c2)
                R[r][c2] = S[perm[r]][perm[c2]];
        int bidx = 0; float bsgn = 1.f;
        for (int a = 0; a < 4; ++a)
            for (int b2 = 0; b2 < 4; ++b2) {
                cpx Pa[2][2], Pb[2][2];
                get_pauli(a, Pa); get_pauli(b2, Pb);
                float ov = 0.f;
                for (int r = 0; r < 4; ++r)
                    for (int c2 = 0; c2 < 4; ++c2) {
                        cpx K = cmul(Pa[r >> 1][c2 >> 1], Pb[r & 1][c2 & 1]);
                        ov += K.re * R[r][c2].re + K.im * R[r][c2].im;
                    }
                ov *= 0.25f;
                if (ov > 0.5f) { bidx = a * 4 + b2; bsgn = 1.f; }
                else if (ov < -0.5f) { bidx = a * 4 + b2; bsgn = -1.f; }
            }
        CIDX[pr] = bidx;
        CSGN[pr] = bsgn;
    }
    __syncthreads();

    // ---- stage 0: S1 = Ring2^dag Z0 Ring2 (single string) ----
    if (tid == 0) {
        float sg = 1.f;
        int cur = ring_conj(3 /* Z on wire 0 */, 2, CIDX, CSGN, sg);
        int k = 0;
        for (int w = 0; w < 8; ++w) {
            const int ltr = (cur >> (2 * w)) & 3;
            if (ltr != 0) { S1w[k] = w; S1l[k] = ltr; ++k; }
        }
        int n = 1;
        for (int i = 0; i < k; ++i) n *= 3;
        S1sgn = sg; S1k = k; S1n = n;
    }
    __syncthreads();

    const int k1 = S1k, n1 = S1n;

    // ---- stage 1: Rot layer-1 conj expansion (3^k1 strings, distinct) ----
    for (int t = tid; t < n1; t += 256) {
        float c = S1sgn;
        int s = 0;
        int tt = t;
        for (int i = 0; i < k1; ++i) {
            const int bl = tt % 3 + 1;  // X=1,Y=2,Z=3
            tt /= 3;
            c *= TR[(8 + S1w[i]) * 16 + S1l[i] * 4 + bl];
            s |= bl << (2 * S1w[i]);
        }
        MIDS[t] = s;
        MIDC[t] = c;
    }
    __syncthreads();

    // ---- stage 2: Ring1 conj (bijection => strings stay distinct) ----
    for (int t = tid; t < n1; t += 256) {
        float sg = 1.f;
        const int s = ring_conj(MIDS[t], 1, CIDX, CSGN, sg);
        MIDS[t] = s;
        MIDC[t] *= sg;
    }
    __syncthreads();

    // ---- scatter into dense 4^8 tensor (wire-reversed index), no atomics ----
    for (int e = tid; e < n1; e += 256) {
        const int s = MIDS[e];
        int d4 = 0;
#pragma unroll
        for (int w = 0; w < 8; ++w)
            d4 |= ((s >> (2 * w)) & 3) << (2 * (7 - w));
        D0[d4] = MIDC[e];
    }
    __syncthreads();

    // ---- dense wire-by-wire layer-0 PTM transform ----
    // Invariant: index = q3 + 3^t * (a + 4*r); output = q3 + 3^t*(P + 3*r).
    // Digit map: P=0 -> I, P=1 -> Z, P=2 -> Y  (letters {0,3,2}).
    {
        int p3t = 1;
#pragma unroll
        for (int t = 0; t < 7; ++t) {
            const int w = 7 - t;
            const float* src = (t & 1) ? D1 : D0;
            float* dst = (t & 1) ? D0 : D1;
            const int n4 = 1 << (2 * (7 - t));
            const int Nout = p3t * 3 * n4;
            float C0[3], C1[3], C2[3], C3[3];
#pragma unroll
            for (int d = 0; d < 3; ++d) {
                const int b = (d == 0) ? 0 : ((d == 1) ? 3 : 2);
                C0[d] = TR[w * 16 + 0 * 4 + b];
                C1[d] = TR[w * 16 + 1 * 4 + b];
                C2[d] = TR[w * 16 + 2 * 4 + b];
                C3[d] = TR[w * 16 + 3 * 4 + b];
            }
            for (int base = tid * 4; base < Nout; base += 1024) {
                float o[4];
#pragma unroll
                for (int u = 0; u < 4; ++u) {
                    const int idx = base + u;
                    const int q3 = idx % p3t;
                    const int rest = idx / p3t;
                    const int P = rest % 3;
                    const int r = rest / 3;
                    const float* ib = src + q3 + p3t * 4 * r;
                    const float i0 = ib[0];
                    const float i1 = ib[p3t];
                    const float i2 = ib[2 * p3t];
                    const float i3 = ib[3 * p3t];
                    const float c0 = (P == 0) ? C0[0] : ((P == 1) ? C0[1] : C0[2]);
                    const float c1 = (P == 0) ? C1[0] : ((P == 1) ? C1[1] : C1[2]);
                    const float c2 = (P == 0) ? C2[0] : ((P == 1) ? C2[1] : C2[2]);
                    const float c3 = (P == 0) ? C3[0] : ((P == 1) ? C3[1] : C3[2]);
                    o[u] = fmaf(i0, c0, fmaf(i1, c1, fmaf(i2, c2, i3 * c3)));
                }
                float4 v{o[0], o[1], o[2], o[3]};
                *(float4*)(dst + base) = v;
            }
            p3t *= 3;
            __syncthreads();
        }
        // t = 7 (wire 0), r == 0; write padded 243x28 alpha layout.
        {
            const float* src = D1;  // t=7 is odd => src = Dp[1]
            float C0[3], C1[3], C2[3], C3[3];
#pragma unroll
            for (int d = 0; d < 3; ++d) {
                const int b = (d == 0) ? 0 : ((d == 1) ? 3 : 2);
                C0[d] = TR[0 * 16 + 0 * 4 + b];
                C1[d] = TR[0 * 16 + 1 * 4 + b];
                C2[d] = TR[0 * 16 + 2 * 4 + b];
                C3[d] = TR[0 * 16 + 3 * 4 + b];
            }
            for (int idx = tid; idx < 6561; idx += 256) {
                const int q3 = idx % 2187;
                const int P = idx / 2187;
                const float* ib = src + q3;
                const float i0 = ib[0];
                const float i1 = ib[2187];
                const float i2 = ib[2 * 2187];
                const float i3 = ib[3 * 2187];
                const float c0 = (P == 0) ? C0[0] : ((P == 1) ? C0[1] : C0[2]);
                const float c1 = (P == 0) ? C1[0] : ((P == 1) ? C1[1] : C1[2]);
                const float c2 = (P == 0) ? C2[0] : ((P == 1) ? C2[1] : C2[2]);
                const float c3 = (P == 0) ? C3[0] : ((P == 1) ? C3[1] : C3[2]);
                const float o = fmaf(i0, c0, fmaf(i1, c1, fmaf(i2, c2, i3 * c3)));
                ALPHA[(idx / 27) * 28 + (idx % 27)] = o;
            }
        }
    }
}

// ---------------------------------------------------------------------------
// Main contraction: 3 threads per element. Block = 192 = 64 elements x 3
// waves; wave p handles k0 = p (wave-uniform alpha addresses -> scalar path).
// ---------------------------------------------------------------------------
__global__ __launch_bounds__(192, 4) void k_main2(const float* __restrict__ x,
                                                  const float* __restrict__ Aq,
                                                  float* __restrict__ out, int batch) {
    __shared__ float red[192];
    const int tid = threadIdx.x;
    const int p = tid >> 6;       // wave id = k0 digit
    const int lane = tid & 63;
    const int e = blockIdx.x * 64 + lane;

    float cw[8], msw[8];
    if (e < batch) {
        const float4* xp = (const float4*)(x + (size_t)e * 8);
        const float4 xa = xp[0], xb = xp[1];
        const float xs[8] = {xa.x, xa.y, xa.z, xa.w, xb.x, xb.y, xb.z, xb.w};
#pragma unroll
        for (int w = 0; w < 8; ++w) {
            float sv, cv;
            __sincosf(xs[w], &sv, &cv);
            cw[w] = cv;
            msw[w] = -sv;
        }
    } else {
#pragma unroll
        for (int w = 0; w < 8; ++w) { cw[w] = 0.f; msw[w] = 0.f; }
    }

    float f567[28];
    {
        const float F5[3] = {1.f, cw[5], msw[5]};
        const float F6[3] = {1.f, cw[6], msw[6]};
        const float F7[3] = {1.f, cw[7], msw[7]};
        int j = 0;
#pragma unroll
        for (int a = 0; a < 3; ++a)
#pragma unroll
            for (int b2 = 0; b2 < 3; ++b2)
#pragma unroll
                for (int c2 = 0; c2 < 3; ++c2) f567[j++] = F5[a] * F6[b2] * F7[c2];
        f567[27] = 0.f;
    }

    const float p0 = (p == 0) ? 1.f : ((p == 1) ? cw[0] : msw[0]);
    float acc = 0.f;
    int base = p * 81 * 28;
    for (int k1 = 0; k1 < 3; ++k1) {
        const float p1 = p0 * ((k1 == 0) ? 1.f : ((k1 == 1) ? cw[1] : msw[1]));
        for (int k2 = 0; k2 < 3; ++k2) {
            const float p2 = p1 * ((k2 == 0) ? 1.f : ((k2 == 1) ? cw[2] : msw[2]));
#pragma unroll
            for (int k3 = 0; k3 < 3; ++k3) {
                const float p3 = p2 * ((k3 == 0) ? 1.f : ((k3 == 1) ? cw[3] : msw[3]));
#pragma unroll
                for (int k4 = 0; k4 < 3; ++k4) {
                    const float p4 = p3 * ((k4 == 0) ? 1.f : ((k4 == 1) ? cw[4] : msw[4]));
                    const float* Ap = Aq + base;  // wave-uniform address
                    float t0 = 0.f, t1 = 0.f, t2 = 0.f, t3v = 0.f;
#pragma unroll
                    for (int j = 0; j < 28; j += 4) {
                        t0  = fmaf(Ap[j + 0], f567[j + 0], t0);
                        t1  = fmaf(Ap[j + 1], f567[j + 1], t1);
                        t2  = fmaf(Ap[j + 2], f567[j + 2], t2);
                        t3v = fmaf(Ap[j + 3], f567[j + 3], t3v);
                    }
                    acc = fmaf((t0 + t1) + (t2 + t3v), p4, acc);
                    base += 28;
                }
            }
        }
    }

    red[tid] = acc;
    __syncthreads();
    if (tid < 64 && e < batch) {
        const float v = red[lane] + red[lane + 64] + red[lane + 128];
        out[e] = (v + 1.f) * 0.5f;
    }
}

// ============================================================================
// Fallback: round-1 direct statevector simulator (used if ws too small).
// ============================================================================
struct c32 { float x, y; };

__device__ __forceinline__ c32 shfl_xor_c(c32 v, int mask) {
    c32 r;
    r.x = __shfl_xor(v.x, mask, 64);
    r.y = __shfl_xor(v.y, mask, 64);
    return r;
}
__device__ __forceinline__ c32 cmadd2(c32 ga, c32 a, c32 gp, c32 p) {
    c32 n;
    n.x = ga.x * a.x - ga.y * a.y + gp.x * p.x - gp.y * p.y;
    n.y = ga.x * a.y + ga.y * a.x + gp.x * p.y + gp.y * p.x;
    return n;
}
__device__ __forceinline__ c32 rx_mix(float c, float s, c32 a, c32 p) {
    c32 n;
    n.x = c * a.x + s * p.y;
    n.y = c * a.y - s * p.x;
    return n;
}
__device__ __forceinline__ void apply_rx(c32 st[4], int lane, int bb, float c, float s) {
    if (bb < 6) {
#pragma unroll
        for (int r = 0; r < 4; ++r) {
            c32 p = shfl_xor_c(st[r], 1 << bb);
            st[r] = rx_mix(c, s, st[r], p);
        }
    } else if (bb == 6) {
        c32 n0 = rx_mix(c, s, st[0], st[1]);
        c32 n1 = rx_mix(c, s, st[1], st[0]);
        c32 n2 = rx_mix(c, s, st[2], st[3]);
        c32 n3 = rx_mix(c, s, st[3], st[2]);
        st[0] = n0; st[1] = n1; st[2] = n2; st[3] = n3;
    } else {
        c32 n0 = rx_mix(c, s, st[0], st[2]);
        c32 n2 = rx_mix(c, s, st[2], st[0]);
        c32 n1 = rx_mix(c, s, st[1], st[3]);
        c32 n3 = rx_mix(c, s, st[3], st[1]);
        st[0] = n0; st[1] = n1; st[2] = n2; st[3] = n3;
    }
}
__device__ __forceinline__ void apply_rot(c32 st[4], int lane, int bb,
                                          c32 g00, c32 g01, c32 g10, c32 g11) {
    if (bb < 6) {
#pragma unroll
        for (int r = 0; r < 4; ++r) {
            c32 p = shfl_xor_c(st[r], 1 << bb);
            bool hi = (lane >> bb) & 1;
            c32 ga, gp;
            ga.x = hi ? g11.x : g00.x;
            ga.y = hi ? g11.y : g00.y;
            gp.x = hi ? g10.x : g01.x;
            gp.y = hi ? g10.y : g01.y;
            st[r] = cmadd2(ga, st[r], gp, p);
        }
    } else if (bb == 6) {
        c32 n0 = cmadd2(g00, st[0], g01, st[1]);
        c32 n1 = cmadd2(g10, st[0], g11, st[1]);
        c32 n2 = cmadd2(g00, st[2], g01, st[3]);
        c32 n3 = cmadd2(g10, st[2], g11, st[3]);
        st[0] = n0; st[1] = n1; st[2] = n2; st[3] = n3;
    } else {
        c32 n0 = cmadd2(g00, st[0], g01, st[2]);
        c32 n2 = cmadd2(g10, st[0], g11, st[2]);
        c32 n1 = cmadd2(g00, st[1], g01, st[3]);
        c32 n3 = cmadd2(g10, st[1], g11, st[3]);
        st[0] = n0; st[1] = n1; st[2] = n2; st[3] = n3;
    }
}
__device__ __forceinline__ void cswap(bool c, c32& a, c32& b) {
    c32 t = a;
    a.x = c ? b.x : a.x; a.y = c ? b.y : a.y;
    b.x = c ? t.x : b.x; b.y = c ? t.y : b.y;
}
__device__ __forceinline__ void apply_cnot(c32 st[4], int lane, int bc, int bt) {
    if (bt < 6) {
        if (bc < 6) {
            bool ctrl = (lane >> bc) & 1;
#pragma unroll
            for (int r = 0; r < 4; ++r) {
                c32 p = shfl_xor_c(st[r], 1 << bt);
                st[r].x = ctrl ? p.x : st[r].x;
                st[r].y = ctrl ? p.y : st[r].y;
            }
        } else {
#pragma unroll
            for (int r = 0; r < 4; ++r) {
                if ((r >> (bc - 6)) & 1) st[r] = shfl_xor_c(st[r], 1 << bt);
            }
        }
    } else {
        if (bc < 6) {
            bool ctrl = (lane >> bc) & 1;
            if (bt == 6) { cswap(ctrl, st[0], st[1]); cswap(ctrl, st[2], st[3]); }
            else         { cswap(ctrl, st[0], st[2]); cswap(ctrl, st[1], st[3]); }
        } else {
            if (bc == 7 && bt == 6) { c32 t = st[2]; st[2] = st[3]; st[3] = t; }
            else if (bc == 6 && bt == 7) { c32 t = st[1]; st[1] = st[3]; st[3] = t; }
        }
    }
}
__global__ __launch_bounds__(256) void qsim_kernel(const float* __restrict__ x,
                                                   const float* __restrict__ theta,
                                                   float* __restrict__ out,
                                                   int batch) {
    __shared__ float rot[2 * 8 * 8];
    const int t = threadIdx.x;
    if (t < 16) {
        const int l = t >> 3, w = t & 7;
        const float phi = theta[(l * 8 + w) * 3 + 0];
        const float th  = theta[(l * 8 + w) * 3 + 1];
        const float om  = theta[(l * 8 + w) * 3 + 2];
        const float c = cosf(0.5f * th), s = sinf(0.5f * th);
        const float p = 0.5f * (phi + om), m = 0.5f * (phi - om);
        float* g = &rot[t * 8];
        g[0] = c * cosf(p);  g[1] = -c * sinf(p);
        g[2] = -s * cosf(m); g[3] = -s * sinf(m);
        g[4] = s * cosf(m);  g[5] = -s * sinf(m);
        g[6] = c * cosf(p);  g[7] = c * sinf(p);
    }
    __syncthreads();
    const int lane = t & 63;
    const int b = blockIdx.x * 4 + (t >> 6);
    if (b >= batch) return;
    float c8 = 0.f, s8 = 0.f;
    if (lane < 8) {
        const float xv = 0.5f * x[b * 8 + lane];
        c8 = cosf(xv); s8 = sinf(xv);
    }
    c32 st[4];
#pragma unroll
    for (int r = 0; r < 4; ++r) { st[r].x = 0.f; st[r].y = 0.f; }
    if (lane == 0) st[0].x = 1.f;
#pragma unroll
    for (int w = 0; w < 8; ++w) {
        const float c = __shfl(c8, w, 64);
        const float s = __shfl(s8, w, 64);
        apply_rx(st, lane, 7 - w, c, s);
    }
#pragma unroll
    for (int l = 0; l < 2; ++l) {
#pragma unroll
        for (int w = 0; w < 8; ++w) {
            const float* g = &rot[(l * 8 + w) * 8];
            c32 g00{g[0], g[1]}, g01{g[2], g[3]}, g10{g[4], g[5]}, g11{g[6], g[7]};
            apply_rot(st, lane, 7 - w, g00, g01, g10, g11);
        }
        const int rr = l + 1;
#pragma unroll
        for (int w = 0; w < 8; ++w) apply_cnot(st, lane, 7 - w, 7 - ((w + rr) & 7));
    }
    float v = st[0].x * st[0].x + st[0].y * st[0].y
            + st[1].x * st[1].x + st[1].y * st[1].y
            - st[2].x * st[2].x - st[2].y * st[2].y
            - st[3].x * st[3].x - st[3].y * st[3].y;
#pragma unroll
    for (int off = 32; off > 0; off >>= 1) v += __shfl_xor(v, off, 64);
    if (lane == 0) out[b] = (v + 1.f) * 0.5f;
}

// ============================================================================
extern "C" void kernel_launch(void* const* d_in, const int* in_sizes, int n_in,
                              void* d_out, int out_size, void* d_ws, size_t ws_size,
                              hipStream_t stream) {
    const float* x     = (const float*)d_in[0];
    const float* theta = (const float*)d_in[1];
    float* out = (float*)d_out;
    const int batch = in_sizes[0] / 8;

    if (ws_size >= (size_t)WS_FLOATS_NEEDED * 4 + 256) {
        float* ws = (float*)d_ws;
        k_alpha<<<dim3(1), dim3(256), 0, stream>>>(theta, ws);
        k_main2<<<dim3((batch + 63) / 64), dim3(192), 0, stream>>>(
            x, ws + OFF_ALPHA, out, batch);
    } else {
        qsim_kernel<<<dim3((batch + 3) / 4), dim3(256), 0, stream>>>(x, theta, out, batch);
    }
}

// Round 5
// 163.698 us; speedup vs baseline: 2.5006x; 1.7235x over previous
//
#include <hip/hip_runtime.h>

// ============================================================================
// theta batch-uniform => M = U^dag Z0 U fixed. Product input state =>
// ev(b) = F1(b)^T * A * F2(b), A = alpha[243 x 27] over {I,Z,Y} strings,
// F1 = m0⊗..⊗m4 (243), F2 = m5⊗m6⊗m7 (27), m_w = {1, cos x_w, -sin x_w}.
//
// k_alpha (1 block): sparse Heisenberg stages (verified r2-r4) -> dense
//   wire-by-wire PTM transform IN LDS (16 sub-tensors, 2 concurrent) ->
//   writes A as f16 MFMA A-fragments (16 tiles of 16x32).
// k_main3: alpha lives in 64 VGPRs/wave; per 16-element group one
//   16x16x32 f16 MFMA per tile computes P = A*F2; F1 contraction on VALU
//   with compile-time digit products. No alpha loads in the loop.
// ============================================================================

typedef _Float16 v8hf __attribute__((ext_vector_type(8)));
typedef float v4f __attribute__((ext_vector_type(4)));

struct cpx { float re, im; };
__device__ __forceinline__ cpx cmul(cpx a, cpx b) {
    return {a.re * b.re - a.im * b.im, a.re * b.im + a.im * b.re};
}

__device__ __forceinline__ void get_pauli(int a, cpx P[2][2]) {
    cpx z{0.f, 0.f};
    P[0][0] = z; P[0][1] = z; P[1][0] = z; P[1][1] = z;
    switch (a) {
        case 0: P[0][0] = {1.f, 0.f}; P[1][1] = {1.f, 0.f}; break;   // I
        case 1: P[0][1] = {1.f, 0.f}; P[1][0] = {1.f, 0.f}; break;   // X
        case 2: P[0][1] = {0.f, -1.f}; P[1][0] = {0.f, 1.f}; break;  // Y
        case 3: P[0][0] = {1.f, 0.f}; P[1][1] = {-1.f, 0.f}; break;  // Z
    }
}

// ws float layout: AF16 (8192 halfs = 4096 float slots) | MIDS(int 6561) |
//                  MIDC(6561) | R(16*729)
#define OFF_AF   0
#define OFF_MIDS 4096
#define OFF_MIDC 10657
#define OFF_R    17218
#define WS_FLOATS_NEEDED 28882

__device__ __forceinline__ int ring_conj(int cur, int r, const int* CIDX,
                                         const float* CSGN, float& sg) {
    for (int w = 7; w >= 0; --w) {
        const int tw = (w + r) & 7;
        const int pc = (cur >> (2 * w)) & 3;
        const int pt = (cur >> (2 * tw)) & 3;
        const int q = pc * 4 + pt;
        const int nq = CIDX[q];
        sg *= CSGN[q];
        cur = (cur & ~((3 << (2 * w)) | (3 << (2 * tw))))
            | ((nq >> 2) << (2 * w)) | ((nq & 3) << (2 * tw));
    }
    return cur;
}

// ---------------------------------------------------------------------------
// Prepass: one block, dense transform in LDS.
// ---------------------------------------------------------------------------
__global__ __launch_bounds__(256) void k_alpha(const float* __restrict__ theta,
                                               float* __restrict__ ws) {
    __shared__ float TR[256];      // 16 gates x 4x4 PTM
    __shared__ float CSGN[16];
    __shared__ int   CIDX[16];
    __shared__ float BIG[14336];   // 2 x (4096 + 3072) working; reused in ph3
    __shared__ int   S1k, S1n;
    __shared__ float S1sgn;
    __shared__ int   S1w[8], S1l[8];

    int*   MIDS = (int*)(ws + OFF_MIDS);
    float* MIDC = ws + OFF_MIDC;
    float* Rg   = ws + OFF_R;
    const int tid = threadIdx.x;

    // zero the f16 fragment region (written sparsely at the end)
    int* AFi = (int*)(ws + OFF_AF);
    for (int i = tid; i < 4096; i += 256) AFi[i] = 0;

    // ---- PTMs (threads 0-15) and CNOT table (threads 64-79), verified r4 ----
    if (tid < 16) {
        const int l = tid >> 3, w = tid & 7;
        const float phi = theta[(l * 8 + w) * 3 + 0];
        const float th  = theta[(l * 8 + w) * 3 + 1];
        const float om  = theta[(l * 8 + w) * 3 + 2];
        const float c = cosf(0.5f * th), s = sinf(0.5f * th);
        const float ps = 0.5f * (phi + om), ms = 0.5f * (phi - om);
        cpx G[2][2];
        G[0][0] = {c * cosf(ps), -c * sinf(ps)};
        G[0][1] = {-s * cosf(ms), -s * sinf(ms)};
        G[1][0] = {s * cosf(ms), -s * sinf(ms)};
        G[1][1] = {c * cosf(ps), c * sinf(ps)};
        for (int a = 0; a < 4; ++a) {
            cpx Pa[2][2]; get_pauli(a, Pa);
            cpx M1[2][2];
            for (int i = 0; i < 2; ++i)
                for (int j = 0; j < 2; ++j) {
                    cpx acc{0.f, 0.f};
                    for (int k = 0; k < 2; ++k) {
                        cpx t = cmul(Pa[i][k], G[k][j]);
                        acc.re += t.re; acc.im += t.im;
                    }
                    M1[i][j] = acc;
                }
            cpx H[2][2];
            for (int i = 0; i < 2; ++i)
                for (int j = 0; j < 2; ++j) {
                    cpx acc{0.f, 0.f};
                    for (int k = 0; k < 2; ++k) {
                        cpx gc{G[k][i].re, -G[k][i].im};
                        cpx t = cmul(gc, M1[k][j]);
                        acc.re += t.re; acc.im += t.im;
                    }
                    H[i][j] = acc;
                }
            for (int b = 0; b < 4; ++b) {
                cpx Pb[2][2]; get_pauli(b, Pb);
                float tr = 0.f;
                for (int i = 0; i < 2; ++i)
                    for (int j = 0; j < 2; ++j)
                        tr += Pb[i][j].re * H[j][i].re - Pb[i][j].im * H[j][i].im;
                TR[tid * 16 + a * 4 + b] = 0.5f * tr;
            }
        }
    }
    if (tid >= 64 && tid < 80) {
        const int pr = tid - 64;
        const int pc = pr >> 2, pt = pr & 3;
        const int perm[4] = {0, 1, 3, 2};
        cpx Pc[2][2], Pt[2][2];
        get_pauli(pc, Pc); get_pauli(pt, Pt);
        cpx S[4][4];
        for (int i = 0; i < 2; ++i)
            for (int j = 0; j < 2; ++j)
                for (int k = 0; k < 2; ++k)
                    for (int l2 = 0; l2 < 2; ++l2)
                        S[2 * i + j][2 * k + l2] = cmul(Pc[i][k], Pt[j][l2]);
        cpx R[4][4];
        for (int r = 0; r < 4; ++r)
            for (int c2 = 0; c2 < 4; ++c2)
                R[r][c2] = S[perm[r]][perm[c2]];
        int bidx = 0; float bsgn = 1.f;
        for (int a = 0; a < 4; ++a)
            for (int b2 = 0; b2 < 4; ++b2) {
                cpx Pa[2][2], Pb[2][2];
                get_pauli(a, Pa); get_pauli(b2, Pb);
                float ov = 0.f;
                for (int r = 0; r < 4; ++r)
                    for (int c2 = 0; c2 < 4; ++c2) {
                        cpx K = cmul(Pa[r >> 1][c2 >> 1], Pb[r & 1][c2 & 1]);
                        ov += K.re * R[r][c2].re + K.im * R[r][c2].im;
                    }
                ov *= 0.25f;
                if (ov > 0.5f) { bidx = a * 4 + b2; bsgn = 1.f; }
                else if (ov < -0.5f) { bidx = a * 4 + b2; bsgn = -1.f; }
            }
        CIDX[pr] = bidx;
        CSGN[pr] = bsgn;
    }
    __syncthreads();

    // ---- stage 0: S1 = Ring2^dag Z0 Ring2 ----
    if (tid == 0) {
        float sg = 1.f;
        int cur = ring_conj(3, 2, CIDX, CSGN, sg);
        int k = 0;
        for (int w = 0; w < 8; ++w) {
            const int ltr = (cur >> (2 * w)) & 3;
            if (ltr != 0) { S1w[k] = w; S1l[k] = ltr; ++k; }
        }
        int n = 1;
        for (int i = 0; i < k; ++i) n *= 3;
        S1sgn = sg; S1k = k; S1n = n;
    }
    __syncthreads();
    const int k1 = S1k, n1 = S1n;

    // ---- stage 1: layer-1 Rot expansion -> MIDS/MIDC (global ws) ----
    for (int t = tid; t < n1; t += 256) {
        float c = S1sgn;
        int s = 0;
        int tt = t;
        for (int i = 0; i < k1; ++i) {
            const int bl = tt % 3 + 1;
            tt /= 3;
            c *= TR[(8 + S1w[i]) * 16 + S1l[i] * 4 + bl];
            s |= bl << (2 * S1w[i]);
        }
        MIDS[t] = s;
        MIDC[t] = c;
    }
    __syncthreads();

    // ---- stage 2: Ring1 conj (bijection) ----
    for (int t = tid; t < n1; t += 256) {
        float sg = 1.f;
        const int s = ring_conj(MIDS[t], 1, CIDX, CSGN, sg);
        MIDS[t] = s;
        MIDC[t] *= sg;
    }
    __syncthreads();

    // ---- phase 2: 16 sub-tensors (wire0,wire1 letters), 2 at a time in LDS.
    // Sub-tensor = 6 wires (2..7), base-4 idx with wire7 least significant.
    const int half = tid >> 7, htid = tid & 127;
    float* Wa = BIG + half * 7168;
    float* Wb = Wa + 4096;
    for (int rnd = 0; rnd < 8; ++rnd) {
        const int sub = rnd * 2 + half;
        const int sa0 = sub >> 2, sa1 = sub & 3;
        for (int i = htid; i < 4096; i += 128) Wa[i] = 0.f;
        __syncthreads();
        for (int e2 = htid; e2 < n1; e2 += 128) {
            const int s = MIDS[e2];
            if (((s & 3) == sa0) && (((s >> 2) & 3) == sa1)) {
                int d4 = 0;
#pragma unroll
                for (int w = 2; w < 8; ++w)
                    d4 |= ((s >> (2 * w)) & 3) << (2 * (7 - w));
                Wa[d4] = MIDC[e2];
            }
        }
        __syncthreads();
        // 6 PTM stages, wires 7..2. invariant idx = q3 + 3^tl*(a + 4r).
        const int P3c[6] = {1, 3, 9, 27, 81, 243};
        const int N4c[6] = {1024, 256, 64, 16, 4, 1};
#pragma unroll
        for (int tl = 0; tl < 6; ++tl) {
            const int w = 7 - tl;
            const float* src = (tl & 1) ? Wb : Wa;
            float* dst = (tl & 1) ? Wa : Wb;
            const int p3 = P3c[tl];
            const int Nout = p3 * 3 * N4c[tl];
            for (int idx = htid; idx < Nout; idx += 128) {
                const int q3 = idx % p3;
                const int rest = idx / p3;
                const int P = rest % 3;
                const int r = rest / 3;
                const int let = (P == 0) ? 0 : ((P == 1) ? 3 : 2);
                const float* ib = src + q3 + p3 * 4 * r;
                dst[idx] = ib[0] * TR[w * 16 + 0 + let]
                         + ib[p3] * TR[w * 16 + 4 + let]
                         + ib[2 * p3] * TR[w * 16 + 8 + let]
                         + ib[3 * p3] * TR[w * 16 + 12 + let];
            }
            __syncthreads();
        }
        // result (729) ends in Wa
        for (int k = htid; k < 729; k += 128) Rg[sub * 729 + k] = Wa[k];
        __syncthreads();
    }

    // ---- phase 3a: wire-1 transform: BIG[a0*2187 + P1*729 + qq] ----
    for (int idx1 = tid; idx1 < 8748; idx1 += 256) {
        const int a0 = idx1 / 2187;
        const int rem = idx1 % 2187;
        const int P1 = rem / 729;
        const int qq = rem % 729;
        const int let = (P1 == 0) ? 0 : ((P1 == 1) ? 3 : 2);
        float v = 0.f;
#pragma unroll
        for (int a1 = 0; a1 < 4; ++a1)
            v += Rg[(a0 * 4 + a1) * 729 + qq] * TR[16 + a1 * 4 + let];
        BIG[idx1] = v;
    }
    __syncthreads();

    // ---- phase 3b: wire-0 transform + scatter into f16 A-fragments.
    // idxF = sum kw*3^(7-w); i = idxF/27 (rows, k0..k4), j = idxF%27 (k5..k7).
    // Fragment: tile t = i>>4, lane = (j>>3)*16 + (i&15), slot jj = j&7.
    _Float16* AF = (_Float16*)(ws + OFF_AF);
    for (int idxF = tid; idxF < 6561; idxF += 256) {
        const int P0 = idxF / 2187;
        const int rest = idxF % 2187;
        const int let = (P0 == 0) ? 0 : ((P0 == 1) ? 3 : 2);
        float v = 0.f;
#pragma unroll
        for (int a0 = 0; a0 < 4; ++a0)
            v += BIG[a0 * 2187 + rest] * TR[a0 * 4 + let];
        const int i = idxF / 27, j = idxF % 27;
        const int t = i >> 4, m = i & 15;
        const int lane = (j >> 3) * 16 + m, jj = j & 7;
        AF[(size_t)(t * 64 + lane) * 8 + jj] = (_Float16)v;
    }
}

// ---------------------------------------------------------------------------
// Main: MFMA stage-1 (j-contraction), VALU stage-2 (i-contraction).
// ---------------------------------------------------------------------------
template <int Q>
__device__ __forceinline__ v8hf build_bfrag(const float* m5v, const float* m6v,
                                            const float* m7v) {
    v8hf bf;
#pragma unroll
    for (int jj = 0; jj < 8; ++jj) {
        const int j = Q * 8 + jj;
        float v = 0.f;
        if (j < 27) {
            const int k5 = j / 9, k6 = (j % 9) / 3, k7 = j % 3;
            v = m5v[k5] * m6v[k6] * m7v[k7];
        }
        bf[jj] = (_Float16)v;
    }
    return bf;
}

template <int Q>
__device__ __forceinline__ float contract_f1(const v4f* acc, const float* m0v,
                                             const float* m1v, const float* m2v,
                                             const float* m3v, const float* m4v) {
    float ev = 0.f;
#pragma unroll
    for (int t = 0; t < 16; ++t) {
#pragma unroll
        for (int s = 0; s < 4; ++s) {
            const int i = 16 * t + 4 * Q + s;
            if (i < 243) {
                const int k0 = i / 81, k1 = (i / 27) % 3, k2 = (i / 9) % 3;
                const int k3 = (i / 3) % 3, k4 = i % 3;
                const float F1 = m0v[k0] * m1v[k1] * m2v[k2] * m3v[k3] * m4v[k4];
                ev = fmaf(F1, acc[t][s], ev);
            }
        }
    }
    return ev;
}

__global__ __launch_bounds__(256, 2) void k_main3(const float* __restrict__ x,
                                                  const float* __restrict__ wsAF,
                                                  float* __restrict__ out,
                                                  int ngroups) {
    const int lane = threadIdx.x & 63;
    const int q = lane >> 4, e = lane & 15;

    // whole alpha matrix as A-fragments: 16 tiles x 4 VGPR, loaded once
    const v8hf* AFp = (const v8hf*)wsAF;
    v8hf af[16];
#pragma unroll
    for (int t = 0; t < 16; ++t) af[t] = AFp[t * 64 + lane];

    const int nw = (gridDim.x * blockDim.x) >> 6;
    const int wid = (blockIdx.x * blockDim.x + threadIdx.x) >> 6;

    for (int g = wid; g < ngroups; g += nw) {
        const int b = g * 16 + e;
        const float4* xp = (const float4*)(x + (size_t)b * 8);
        const float4 xa = xp[0], xb = xp[1];
        float m0v[3], m1v[3], m2v[3], m3v[3], m4v[3], m5v[3], m6v[3], m7v[3];
        {
            float sv, cv;
            __sincosf(xa.x, &sv, &cv); m0v[0] = 1.f; m0v[1] = cv; m0v[2] = -sv;
            __sincosf(xa.y, &sv, &cv); m1v[0] = 1.f; m1v[1] = cv; m1v[2] = -sv;
            __sincosf(xa.z, &sv, &cv); m2v[0] = 1.f; m2v[1] = cv; m2v[2] = -sv;
            __sincosf(xa.w, &sv, &cv); m3v[0] = 1.f; m3v[1] = cv; m3v[2] = -sv;
            __sincosf(xb.x, &sv, &cv); m4v[0] = 1.f; m4v[1] = cv; m4v[2] = -sv;
            __sincosf(xb.y, &sv, &cv); m5v[0] = 1.f; m5v[1] = cv; m5v[2] = -sv;
            __sincosf(xb.z, &sv, &cv); m6v[0] = 1.f; m6v[1] = cv; m6v[2] = -sv;
            __sincosf(xb.w, &sv, &cv); m7v[0] = 1.f; m7v[1] = cv; m7v[2] = -sv;
        }

        v8hf bf;
        if (q == 0)      bf = build_bfrag<0>(m5v, m6v, m7v);
        else if (q == 1) bf = build_bfrag<1>(m5v, m6v, m7v);
        else if (q == 2) bf = build_bfrag<2>(m5v, m6v, m7v);
        else             bf = build_bfrag<3>(m5v, m6v, m7v);

        const v4f zero = {0.f, 0.f, 0.f, 0.f};
        v4f acc[16];
#pragma unroll
        for (int t = 0; t < 16; ++t)
            acc[t] = __builtin_amdgcn_mfma_f32_16x16x32_f16(af[t], bf, zero, 0, 0, 0);

        float ev;
        if (q == 0)      ev = contract_f1<0>(acc, m0v, m1v, m2v, m3v, m4v);
        else if (q == 1) ev = contract_f1<1>(acc, m0v, m1v, m2v, m3v, m4v);
        else if (q == 2) ev = contract_f1<2>(acc, m0v, m1v, m2v, m3v, m4v);
        else             ev = contract_f1<3>(acc, m0v, m1v, m2v, m3v, m4v);

        ev += __shfl_xor(ev, 16, 64);
        ev += __shfl_xor(ev, 32, 64);
        if (lane < 16) out[b] = (ev + 1.f) * 0.5f;
    }
}

// ============================================================================
// Fallback: round-1 direct statevector simulator (used if ws too small).
// ============================================================================
struct c32 { float x, y; };

__device__ __forceinline__ c32 shfl_xor_c(c32 v, int mask) {
    c32 r;
    r.x = __shfl_xor(v.x, mask, 64);
    r.y = __shfl_xor(v.y, mask, 64);
    return r;
}
__device__ __forceinline__ c32 cmadd2(c32 ga, c32 a, c32 gp, c32 p) {
    c32 n;
    n.x = ga.x * a.x - ga.y * a.y + gp.x * p.x - gp.y * p.y;
    n.y = ga.x * a.y + ga.y * a.x + gp.x * p.y + gp.y * p.x;
    return n;
}
__device__ __forceinline__ c32 rx_mix(float c, float s, c32 a, c32 p) {
    c32 n;
    n.x = c * a.x + s * p.y;
    n.y = c * a.y - s * p.x;
    return n;
}
__device__ __forceinline__ void apply_rx(c32 st[4], int lane, int bb, float c, float s) {
    if (bb < 6) {
#pragma unroll
        for (int r = 0; r < 4; ++r) {
            c32 p = shfl_xor_c(st[r], 1 << bb);
            st[r] = rx_mix(c, s, st[r], p);
        }
    } else if (bb == 6) {
        c32 n0 = rx_mix(c, s, st[0], st[1]);
        c32 n1 = rx_mix(c, s, st[1], st[0]);
        c32 n2 = rx_mix(c, s, st[2], st[3]);
        c32 n3 = rx_mix(c, s, st[3], st[2]);
        st[0] = n0; st[1] = n1; st[2] = n2; st[3] = n3;
    } else {
        c32 n0 = rx_mix(c, s, st[0], st[2]);
        c32 n2 = rx_mix(c, s, st[2], st[0]);
        c32 n1 = rx_mix(c, s, st[1], st[3]);
        c32 n3 = rx_mix(c, s, st[3], st[1]);
        st[0] = n0; st[1] = n1; st[2] = n2; st[3] = n3;
    }
}
__device__ __forceinline__ void apply_rot(c32 st[4], int lane, int bb,
                                          c32 g00, c32 g01, c32 g10, c32 g11) {
    if (bb < 6) {
#pragma unroll
        for (int r = 0; r < 4; ++r) {
            c32 p = shfl_xor_c(st[r], 1 << bb);
            bool hi = (lane >> bb) & 1;
            c32 ga, gp;
            ga.x = hi ? g11.x : g00.x;
            ga.y = hi ? g11.y : g00.y;
            gp.x = hi ? g10.x : g01.x;
            gp.y = hi ? g10.y : g01.y;
            st[r] = cmadd2(ga, st[r], gp, p);
        }
    } else if (bb == 6) {
        c32 n0 = cmadd2(g00, st[0], g01, st[1]);
        c32 n1 = cmadd2(g10, st[0], g11, st[1]);
        c32 n2 = cmadd2(g00, st[2], g01, st[3]);
        c32 n3 = cmadd2(g10, st[2], g11, st[3]);
        st[0] = n0; st[1] = n1; st[2] = n2; st[3] = n3;
    } else {
        c32 n0 = cmadd2(g00, st[0], g01, st[2]);
        c32 n2 = cmadd2(g10, st[0], g11, st[2]);
        c32 n1 = cmadd2(g00, st[1], g01, st[3]);
        c32 n3 = cmadd2(g10, st[1], g11, st[3]);
        st[0] = n0; st[1] = n1; st[2] = n2; st[3] = n3;
    }
}
__device__ __forceinline__ void cswap(bool c, c32& a, c32& b) {
    c32 t = a;
    a.x = c ? b.x : a.x; a.y = c ? b.y : a.y;
    b.x = c ? t.x : b.x; b.y = c ? t.y : b.y;
}
__device__ __forceinline__ void apply_cnot(c32 st[4], int lane, int bc, int bt) {
    if (bt < 6) {
        if (bc < 6) {
            bool ctrl = (lane >> bc) & 1;
#pragma unroll
            for (int r = 0; r < 4; ++r) {
                c32 p = shfl_xor_c(st[r], 1 << bt);
                st[r].x = ctrl ? p.x : st[r].x;
                st[r].y = ctrl ? p.y : st[r].y;
            }
        } else {
#pragma unroll
            for (int r = 0; r < 4; ++r) {
                if ((r >> (bc - 6)) & 1) st[r] = shfl_xor_c(st[r], 1 << bt);
            }
        }
    } else {
        if (bc < 6) {
            bool ctrl = (lane >> bc) & 1;
            if (bt == 6) { cswap(ctrl, st[0], st[1]); cswap(ctrl, st[2], st[3]); }
            else         { cswap(ctrl, st[0], st[2]); cswap(ctrl, st[1], st[3]); }
        } else {
            if (bc == 7 && bt == 6) { c32 t = st[2]; st[2] = st[3]; st[3] = t; }
            else if (bc == 6 && bt == 7) { c32 t = st[1]; st[1] = st[3]; st[3] = t; }
        }
    }
}
__global__ __launch_bounds__(256) void qsim_kernel(const float* __restrict__ x,
                                                   const float* __restrict__ theta,
                                                   float* __restrict__ out,
                                                   int batch) {
    __shared__ float rot[2 * 8 * 8];
    const int t = threadIdx.x;
    if (t < 16) {
        const int l = t >> 3, w = t & 7;
        const float phi = theta[(l * 8 + w) * 3 + 0];
        const float th  = theta[(l * 8 + w) * 3 + 1];
        const float om  = theta[(l * 8 + w) * 3 + 2];
        const float c = cosf(0.5f * th), s = sinf(0.5f * th);
        const float p = 0.5f * (phi + om), m = 0.5f * (phi - om);
        float* g = &rot[t * 8];
        g[0] = c * cosf(p);  g[1] = -c * sinf(p);
        g[2] = -s * cosf(m); g[3] = -s * sinf(m);
        g[4] = s * cosf(m);  g[5] = -s * sinf(m);
        g[6] = c * cosf(p);  g[7] = c * sinf(p);
    }
    __syncthreads();
    const int lane = t & 63;
    const int b = blockIdx.x * 4 + (t >> 6);
    if (b >= batch) return;
    float c8 = 0.f, s8 = 0.f;
    if (lane < 8) {
        const float xv = 0.5f * x[b * 8 + lane];
        c8 = cosf(xv); s8 = sinf(xv);
    }
    c32 st[4];
#pragma unroll
    for (int r = 0; r < 4; ++r) { st[r].x = 0.f; st[r].y = 0.f; }
    if (lane == 0) st[0].x = 1.f;
#pragma unroll
    for (int w = 0; w < 8; ++w) {
        const float c = __shfl(c8, w, 64);
        const float s = __shfl(s8, w, 64);
        apply_rx(st, lane, 7 - w, c, s);
    }
#pragma unroll
    for (int l = 0; l < 2; ++l) {
#pragma unroll
        for (int w = 0; w < 8; ++w) {
            const float* g = &rot[(l * 8 + w) * 8];
            c32 g00{g[0], g[1]}, g01{g[2], g[3]}, g10{g[4], g[5]}, g11{g[6], g[7]};
            apply_rot(st, lane, 7 - w, g00, g01, g10, g11);
        }
        const int rr = l + 1;
#pragma unroll
        for (int w = 0; w < 8; ++w) apply_cnot(st, lane, 7 - w, 7 - ((w + rr) & 7));
    }
    float v = st[0].x * st[0].x + st[0].y * st[0].y
            + st[1].x * st[1].x + st[1].y * st[1].y
            - st[2].x * st[2].x - st[2].y * st[2].y
            - st[3].x * st[3].x - st[3].y * st[3].y;
#pragma unroll
    for (int off = 32; off > 0; off >>= 1) v += __shfl_xor(v, off, 64);
    if (lane == 0) out[b] = (v + 1.f) * 0.5f;
}

// ============================================================================
extern "C" void kernel_launch(void* const* d_in, const int* in_sizes, int n_in,
                              void* d_out, int out_size, void* d_ws, size_t ws_size,
                              hipStream_t stream) {
    const float* x     = (const float*)d_in[0];
    const float* theta = (const float*)d_in[1];
    float* out = (float*)d_out;
    const int batch = in_sizes[0] / 8;

    if (ws_size >= (size_t)WS_FLOATS_NEEDED * 4 + 256 && (batch & 15) == 0) {
        float* ws = (float*)d_ws;
        k_alpha<<<dim3(1), dim3(256), 0, stream>>>(theta, ws);
        const int ngroups = batch / 16;
        k_main3<<<dim3(512), dim3(256), 0, stream>>>(x, ws + OFF_AF, out, ngroups);
    } else {
        qsim_kernel<<<dim3((batch + 3) / 4), dim3(256), 0, stream>>>(x, theta, out, batch);
    }
}

// Round 6
// 81.897 us; speedup vs baseline: 4.9983x; 1.9988x over previous
//
#include <hip/hip_runtime.h>

// ============================================================================
// theta batch-uniform => M = U^dag Z0 U fixed. Product input state =>
// ev(b) = F1(b)^T * A * F2(b), A = alpha[243 x 27] over {I,Z,Y} strings,
// F1 = m0⊗..⊗m4 (243), F2 = m5⊗m6⊗m7 (27), m_w = {1, cos x_w, -sin x_w}.
//
// Prepass now parallel across CUs (math identical to round-5-verified):
//   k_sub (16 blocks x 1024): per (wire0,wire1)-letter sub-tensor: PTMs +
//     CNOT table + sparse Heisenberg stages in-block, scatter matching
//     strings into LDS, 6-stage wire PTM transform in LDS, write Rg[729].
//   k_fin (1 block x 1024): wire-1 + wire-0 transforms (LDS intermediate),
//     writes the full f16 MFMA A-fragment region (all slots, packed ints).
// k_main4: per 16-element group: 16 f16 16x16x32 MFMAs (A-frags from L1)
//   + q-templated VALU contraction with pair-product F1.
// ============================================================================

typedef _Float16 v8hf __attribute__((ext_vector_type(8)));
typedef float v4f __attribute__((ext_vector_type(4)));

struct cpx { float re, im; };
__device__ __forceinline__ cpx cmul(cpx a, cpx b) {
    return {a.re * b.re - a.im * b.im, a.re * b.im + a.im * b.re};
}

__device__ __forceinline__ void get_pauli(int a, cpx P[2][2]) {
    cpx z{0.f, 0.f};
    P[0][0] = z; P[0][1] = z; P[1][0] = z; P[1][1] = z;
    switch (a) {
        case 0: P[0][0] = {1.f, 0.f}; P[1][1] = {1.f, 0.f}; break;   // I
        case 1: P[0][1] = {1.f, 0.f}; P[1][0] = {1.f, 0.f}; break;   // X
        case 2: P[0][1] = {0.f, -1.f}; P[1][0] = {0.f, 1.f}; break;  // Y
        case 3: P[0][0] = {1.f, 0.f}; P[1][1] = {-1.f, 0.f}; break;  // Z
    }
}

// PTM for Rot gate (layer l, wire w): out[a*4+b] = 0.5 Re Tr(sig_b G^dag sig_a G)
__device__ void compute_ptm(const float* __restrict__ theta, int l, int w,
                            float* out) {
    const float phi = theta[(l * 8 + w) * 3 + 0];
    const float th  = theta[(l * 8 + w) * 3 + 1];
    const float om  = theta[(l * 8 + w) * 3 + 2];
    const float c = cosf(0.5f * th), s = sinf(0.5f * th);
    const float ps = 0.5f * (phi + om), ms = 0.5f * (phi - om);
    cpx G[2][2];
    G[0][0] = {c * cosf(ps), -c * sinf(ps)};
    G[0][1] = {-s * cosf(ms), -s * sinf(ms)};
    G[1][0] = {s * cosf(ms), -s * sinf(ms)};
    G[1][1] = {c * cosf(ps), c * sinf(ps)};
    for (int a = 0; a < 4; ++a) {
        cpx Pa[2][2]; get_pauli(a, Pa);
        cpx M1[2][2];
        for (int i = 0; i < 2; ++i)
            for (int j = 0; j < 2; ++j) {
                cpx acc{0.f, 0.f};
                for (int k = 0; k < 2; ++k) {
                    cpx t = cmul(Pa[i][k], G[k][j]);
                    acc.re += t.re; acc.im += t.im;
                }
                M1[i][j] = acc;
            }
        cpx H[2][2];
        for (int i = 0; i < 2; ++i)
            for (int j = 0; j < 2; ++j) {
                cpx acc{0.f, 0.f};
                for (int k = 0; k < 2; ++k) {
                    cpx gc{G[k][i].re, -G[k][i].im};
                    cpx t = cmul(gc, M1[k][j]);
                    acc.re += t.re; acc.im += t.im;
                }
                H[i][j] = acc;
            }
        for (int b = 0; b < 4; ++b) {
            cpx Pb[2][2]; get_pauli(b, Pb);
            float tr = 0.f;
            for (int i = 0; i < 2; ++i)
                for (int j = 0; j < 2; ++j)
                    tr += Pb[i][j].re * H[j][i].re - Pb[i][j].im * H[j][i].im;
            out[a * 4 + b] = 0.5f * tr;
        }
    }
}

// CNOT conjugation table entry pr = pc*4+pt -> (idx, sign)
__device__ void compute_cnot_entry(int pr, int* oidx, float* osgn) {
    const int pc = pr >> 2, pt = pr & 3;
    const int perm[4] = {0, 1, 3, 2};
    cpx Pc[2][2], Pt[2][2];
    get_pauli(pc, Pc); get_pauli(pt, Pt);
    cpx S[4][4];
    for (int i = 0; i < 2; ++i)
        for (int j = 0; j < 2; ++j)
            for (int k = 0; k < 2; ++k)
                for (int l2 = 0; l2 < 2; ++l2)
                    S[2 * i + j][2 * k + l2] = cmul(Pc[i][k], Pt[j][l2]);
    cpx R[4][4];
    for (int r = 0; r < 4; ++r)
        for (int c2 = 0; c2 < 4; ++c2)
            R[r][c2] = S[perm[r]][perm[c2]];
    int bidx = 0; float bsgn = 1.f;
    for (int a = 0; a < 4; ++a)
        for (int b2 = 0; b2 < 4; ++b2) {
            cpx Pa[2][2], Pb[2][2];
            get_pauli(a, Pa); get_pauli(b2, Pb);
            float ov = 0.f;
            for (int r = 0; r < 4; ++r)
                for (int c2 = 0; c2 < 4; ++c2) {
                    cpx K = cmul(Pa[r >> 1][c2 >> 1], Pb[r & 1][c2 & 1]);
                    ov += K.re * R[r][c2].re + K.im * R[r][c2].im;
                }
            ov *= 0.25f;
            if (ov > 0.5f) { bidx = a * 4 + b2; bsgn = 1.f; }
            else if (ov < -0.5f) { bidx = a * 4 + b2; bsgn = -1.f; }
        }
    *oidx = bidx;
    *osgn = bsgn;
}

// ws float layout: AF16 (8192 halfs = 4096 float slots) | Rg[16*729]
#define OFF_AF 0
#define OFF_R  4096
#define WS_FLOATS_NEEDED (4096 + 16 * 729)

__device__ __forceinline__ int ring_conj(int cur, int r, const int* CIDX,
                                         const float* CSGN, float& sg) {
    for (int w = 7; w >= 0; --w) {
        const int tw = (w + r) & 7;
        const int pc = (cur >> (2 * w)) & 3;
        const int pt = (cur >> (2 * tw)) & 3;
        const int q = pc * 4 + pt;
        const int nq = CIDX[q];
        sg *= CSGN[q];
        cur = (cur & ~((3 << (2 * w)) | (3 << (2 * tw))))
            | ((nq >> 2) << (2 * w)) | ((nq & 3) << (2 * tw));
    }
    return cur;
}

// ---------------------------------------------------------------------------
// k_sub: one block per (wire0,wire1)-letter pair. Self-contained.
// ---------------------------------------------------------------------------
__global__ __launch_bounds__(1024) void k_sub(const float* __restrict__ theta,
                                              float* __restrict__ ws) {
    __shared__ float TR[256];
    __shared__ float CSGN[16];
    __shared__ int   CIDX[16];
    __shared__ float Wa[4096];
    __shared__ float Wb[3072];
    __shared__ int   S1k, S1n;
    __shared__ float S1sgn;
    __shared__ int   S1w[8], S1l[8];

    const int tid = threadIdx.x;
    const int sub = blockIdx.x;
    const int sa0 = sub >> 2, sa1 = sub & 3;
    float* Rg = ws + OFF_R;

    if (tid < 16) compute_ptm(theta, tid >> 3, tid & 7, &TR[tid * 16]);
    if (tid >= 64 && tid < 80) compute_cnot_entry(tid - 64, &CIDX[tid - 64], &CSGN[tid - 64]);
    for (int i = tid; i < 4096; i += 1024) Wa[i] = 0.f;
    __syncthreads();

    // stage 0: S1 = Ring2^dag Z0 Ring2 (single string)
    if (tid == 0) {
        float sg = 1.f;
        int cur = ring_conj(3 /* Z on wire 0 */, 2, CIDX, CSGN, sg);
        int k = 0;
        for (int w = 0; w < 8; ++w) {
            const int ltr = (cur >> (2 * w)) & 3;
            if (ltr != 0) { S1w[k] = w; S1l[k] = ltr; ++k; }
        }
        int n = 1;
        for (int i = 0; i < k; ++i) n *= 3;
        S1sgn = sg; S1k = k; S1n = n;
    }
    __syncthreads();
    const int k1 = S1k, n1 = S1n;

    // stages 1+2 + filter + scatter (strings distinct => no collisions)
    for (int t = tid; t < n1; t += 1024) {
        float c = S1sgn;
        int s = 0;
        int tt = t;
        for (int i = 0; i < k1; ++i) {
            const int bl = tt % 3 + 1;  // X=1,Y=2,Z=3
            tt /= 3;
            c *= TR[(8 + S1w[i]) * 16 + S1l[i] * 4 + bl];
            s |= bl << (2 * S1w[i]);
        }
        float sg = 1.f;
        s = ring_conj(s, 1, CIDX, CSGN, sg);
        c *= sg;
        if (((s & 3) == sa0) && (((s >> 2) & 3) == sa1)) {
            int d4 = 0;
#pragma unroll
            for (int w = 2; w < 8; ++w)
                d4 |= ((s >> (2 * w)) & 3) << (2 * (7 - w));
            Wa[d4] = c;
        }
    }
    __syncthreads();

    // 6 PTM stages, wires 7..2. invariant idx = q3 + 3^tl*(a + 4r).
    const int P3c[6] = {1, 3, 9, 27, 81, 243};
    const int N4c[6] = {1024, 256, 64, 16, 4, 1};
#pragma unroll
    for (int tl = 0; tl < 6; ++tl) {
        const int w = 7 - tl;
        const float* src = (tl & 1) ? Wb : Wa;
        float* dst = (tl & 1) ? Wa : Wb;
        const int p3 = P3c[tl];
        const int Nout = p3 * 3 * N4c[tl];
        for (int idx = tid; idx < Nout; idx += 1024) {
            const int q3 = idx % p3;
            const int rest = idx / p3;
            const int P = rest % 3;
            const int r = rest / 3;
            const int let = (P == 0) ? 0 : ((P == 1) ? 3 : 2);
            const float* ib = src + q3 + p3 * 4 * r;
            dst[idx] = ib[0] * TR[w * 16 + 0 + let]
                     + ib[p3] * TR[w * 16 + 4 + let]
                     + ib[2 * p3] * TR[w * 16 + 8 + let]
                     + ib[3 * p3] * TR[w * 16 + 12 + let];
        }
        __syncthreads();
    }
    // result (729) ends in Wa
    for (int k = tid; k < 729; k += 1024) Rg[sub * 729 + k] = Wa[k];
}

// ---------------------------------------------------------------------------
// k_fin: wire-1 + wire-0 transforms; write full AF region (packed int writes).
// ---------------------------------------------------------------------------
__global__ __launch_bounds__(1024) void k_fin(const float* __restrict__ theta,
                                              float* __restrict__ ws) {
    __shared__ float BIG[8748];
    __shared__ float TRw[32];  // gate (l=0,w=0) in [0..15], (l=0,w=1) in [16..31]
    const int tid = threadIdx.x;
    if (tid < 2) compute_ptm(theta, 0, tid, &TRw[tid * 16]);
    __syncthreads();

    const float* Rg = ws + OFF_R;
    // 3a: wire-1 transform: BIG[a0*2187 + P1*729 + qq]
    for (int idx1 = tid; idx1 < 8748; idx1 += 1024) {
        const int a0 = idx1 / 2187;
        const int rem = idx1 % 2187;
        const int P1 = rem / 729;
        const int qq = rem % 729;
        const int let = (P1 == 0) ? 0 : ((P1 == 1) ? 3 : 2);
        float v = 0.f;
#pragma unroll
        for (int a1 = 0; a1 < 4; ++a1)
            v += Rg[(a0 * 4 + a1) * 729 + qq] * TRw[16 + a1 * 4 + let];
        BIG[idx1] = v;
    }
    __syncthreads();

    // 3b: wire-0 transform + full-coverage packed write of AF.
    // half index h = (t*64+lane)*8 + jj; int slot u = h/2.
    // t = u>>8, lane = (u>>2)&63, jj0 = (u&3)*2; m = lane&15; i = t*16+m;
    // j = (lane>>4)*8 + jj; valid iff i<243 && j<27; idxF = i*27+j.
    int* AFi = (int*)(ws + OFF_AF);
    for (int u = tid; u < 4096; u += 1024) {
        const int t = u >> 8;
        const int lane = (u >> 2) & 63;
        const int jj0 = (u & 3) * 2;
        const int m = lane & 15;
        const int i = t * 16 + m;
        const int jb = (lane >> 4) * 8;
        unsigned int packed = 0;
#pragma unroll
        for (int z = 0; z < 2; ++z) {
            const int j = jb + jj0 + z;
            float v = 0.f;
            if (i < 243 && j < 27) {
                const int idxF = i * 27 + j;
                const int P0 = idxF / 2187;
                const int rest = idxF % 2187;
                const int let = (P0 == 0) ? 0 : ((P0 == 1) ? 3 : 2);
                v = BIG[rest] * TRw[0 + let]
                  + BIG[2187 + rest] * TRw[4 + let]
                  + BIG[2 * 2187 + rest] * TRw[8 + let]
                  + BIG[3 * 2187 + rest] * TRw[12 + let];
            }
            const _Float16 hv = (_Float16)v;
            const unsigned short bits = __builtin_bit_cast(unsigned short, hv);
            packed |= ((unsigned int)bits) << (16 * z);
        }
        AFi[u] = (int)packed;
    }
}

// ---------------------------------------------------------------------------
// Main: MFMA stage-1 (j-contraction), q-templated VALU stage-2 with
// pair-product F1 (P01 = m0⊗m1, P23 = m2⊗m3).
// ---------------------------------------------------------------------------
template <int Q>
__device__ __forceinline__ v8hf build_bfrag(const float* m5v, const float* m6v,
                                            const float* m7v) {
    v8hf bf;
#pragma unroll
    for (int jj = 0; jj < 8; ++jj) {
        const int j = Q * 8 + jj;
        float v = 0.f;
        if (j < 27) {
            const int k5 = j / 9, k6 = (j % 9) / 3, k7 = j % 3;
            v = m5v[k5] * m6v[k6] * m7v[k7];
        }
        bf[jj] = (_Float16)v;
    }
    return bf;
}

template <int Q>
__device__ __forceinline__ float contract_f1(const v4f* acc, const float* P01,
                                             const float* P23, const float* m4v) {
    float ev = 0.f;
#pragma unroll
    for (int t = 0; t < 16; ++t) {
#pragma unroll
        for (int s = 0; s < 4; ++s) {
            const int i = 16 * t + 4 * Q + s;
            if (i < 243) {
                const int u = i / 27, vv = (i % 27) / 3, w = i % 3;
                float f = P01[u] * P23[vv];
                if (w != 0) f *= m4v[w];
                ev = fmaf(f, acc[t][s], ev);
            }
        }
    }
    return ev;
}

__global__ __launch_bounds__(256, 2) void k_main4(const float* __restrict__ x,
                                                  const float* __restrict__ wsAF,
                                                  float* __restrict__ out,
                                                  int ngroups) {
    const int lane = threadIdx.x & 63;
    const int q = lane >> 4, e = lane & 15;
    const int wid = (blockIdx.x * blockDim.x + threadIdx.x) >> 6;
    if (wid >= ngroups) return;

    const int b = wid * 16 + e;
    const float4* xp = (const float4*)(x + (size_t)b * 8);
    const float4 xa = xp[0], xb = xp[1];
    float m0v[3], m1v[3], m2v[3], m3v[3], m4v[3], m5v[3], m6v[3], m7v[3];
    {
        float sv, cv;
        __sincosf(xa.x, &sv, &cv); m0v[0] = 1.f; m0v[1] = cv; m0v[2] = -sv;
        __sincosf(xa.y, &sv, &cv); m1v[0] = 1.f; m1v[1] = cv; m1v[2] = -sv;
        __sincosf(xa.z, &sv, &cv); m2v[0] = 1.f; m2v[1] = cv; m2v[2] = -sv;
        __sincosf(xa.w, &sv, &cv); m3v[0] = 1.f; m3v[1] = cv; m3v[2] = -sv;
        __sincosf(xb.x, &sv, &cv); m4v[0] = 1.f; m4v[1] = cv; m4v[2] = -sv;
        __sincosf(xb.y, &sv, &cv); m5v[0] = 1.f; m5v[1] = cv; m5v[2] = -sv;
        __sincosf(xb.z, &sv, &cv); m6v[0] = 1.f; m6v[1] = cv; m6v[2] = -sv;
        __sincosf(xb.w, &sv, &cv); m7v[0] = 1.f; m7v[1] = cv; m7v[2] = -sv;
    }

    v8hf bf;
    if (q == 0)      bf = build_bfrag<0>(m5v, m6v, m7v);
    else if (q == 1) bf = build_bfrag<1>(m5v, m6v, m7v);
    else if (q == 2) bf = build_bfrag<2>(m5v, m6v, m7v);
    else             bf = build_bfrag<3>(m5v, m6v, m7v);

    // pair products for F1
    float P01[9], P23[9];
#pragma unroll
    for (int a = 0; a < 3; ++a)
#pragma unroll
        for (int b2 = 0; b2 < 3; ++b2) {
            P01[a * 3 + b2] = m0v[a] * m1v[b2];
            P23[a * 3 + b2] = m2v[a] * m3v[b2];
        }

    const v4f zero = {0.f, 0.f, 0.f, 0.f};
    const v8hf* AFp = (const v8hf*)wsAF;
    v4f acc[16];
#pragma unroll
    for (int t = 0; t < 16; ++t)
        acc[t] = __builtin_amdgcn_mfma_f32_16x16x32_f16(AFp[t * 64 + lane], bf, zero, 0, 0, 0);

    float ev;
    if (q == 0)      ev = contract_f1<0>(acc, P01, P23, m4v);
    else if (q == 1) ev = contract_f1<1>(acc, P01, P23, m4v);
    else if (q == 2) ev = contract_f1<2>(acc, P01, P23, m4v);
    else             ev = contract_f1<3>(acc, P01, P23, m4v);

    ev += __shfl_xor(ev, 16, 64);
    ev += __shfl_xor(ev, 32, 64);
    if (lane < 16) out[b] = (ev + 1.f) * 0.5f;
}

// ============================================================================
// Fallback: round-1 direct statevector simulator (used if ws too small).
// ============================================================================
struct c32 { float x, y; };

__device__ __forceinline__ c32 shfl_xor_c(c32 v, int mask) {
    c32 r;
    r.x = __shfl_xor(v.x, mask, 64);
    r.y = __shfl_xor(v.y, mask, 64);
    return r;
}
__device__ __forceinline__ c32 cmadd2(c32 ga, c32 a, c32 gp, c32 p) {
    c32 n;
    n.x = ga.x * a.x - ga.y * a.y + gp.x * p.x - gp.y * p.y;
    n.y = ga.x * a.y + ga.y * a.x + gp.x * p.y + gp.y * p.x;
    return n;
}
__device__ __forceinline__ c32 rx_mix(float c, float s, c32 a, c32 p) {
    c32 n;
    n.x = c * a.x + s * p.y;
    n.y = c * a.y - s * p.x;
    return n;
}
__device__ __forceinline__ void apply_rx(c32 st[4], int lane, int bb, float c, float s) {
    if (bb < 6) {
#pragma unroll
        for (int r = 0; r < 4; ++r) {
            c32 p = shfl_xor_c(st[r], 1 << bb);
            st[r] = rx_mix(c, s, st[r], p);
        }
    } else if (bb == 6) {
        c32 n0 = rx_mix(c, s, st[0], st[1]);
        c32 n1 = rx_mix(c, s, st[1], st[0]);
        c32 n2 = rx_mix(c, s, st[2], st[3]);
        c32 n3 = rx_mix(c, s, st[3], st[2]);
        st[0] = n0; st[1] = n1; st[2] = n2; st[3] = n3;
    } else {
        c32 n0 = rx_mix(c, s, st[0], st[2]);
        c32 n2 = rx_mix(c, s, st[2], st[0]);
        c32 n1 = rx_mix(c, s, st[1], st[3]);
        c32 n3 = rx_mix(c, s, st[3], st[1]);
        st[0] = n0; st[1] = n1; st[2] = n2; st[3] = n3;
    }
}
__device__ __forceinline__ void apply_rot(c32 st[4], int lane, int bb,
                                          c32 g00, c32 g01, c32 g10, c32 g11) {
    if (bb < 6) {
#pragma unroll
        for (int r = 0; r < 4; ++r) {
            c32 p = shfl_xor_c(st[r], 1 << bb);
            bool hi = (lane >> bb) & 1;
            c32 ga, gp;
            ga.x = hi ? g11.x : g00.x;
            ga.y = hi ? g11.y : g00.y;
            gp.x = hi ? g10.x : g01.x;
            gp.y = hi ? g10.y : g01.y;
            st[r] = cmadd2(ga, st[r], gp, p);
        }
    } else if (bb == 6) {
        c32 n0 = cmadd2(g00, st[0], g01, st[1]);
        c32 n1 = cmadd2(g10, st[0], g11, st[1]);
        c32 n2 = cmadd2(g00, st[2], g01, st[3]);
        c32 n3 = cmadd2(g10, st[2], g11, st[3]);
        st[0] = n0; st[1] = n1; st[2] = n2; st[3] = n3;
    } else {
        c32 n0 = cmadd2(g00, st[0], g01, st[2]);
        c32 n2 = cmadd2(g10, st[0], g11, st[2]);
        c32 n1 = cmadd2(g00, st[1], g01, st[3]);
        c32 n3 = cmadd2(g10, st[1], g11, st[3]);
        st[0] = n0; st[1] = n1; st[2] = n2; st[3] = n3;
    }
}
__device__ __forceinline__ void cswap(bool c, c32& a, c32& b) {
    c32 t = a;
    a.x = c ? b.x : a.x; a.y = c ? b.y : a.y;
    b.x = c ? t.x : b.x; b.y = c ? t.y : b.y;
}
__device__ __forceinline__ void apply_cnot(c32 st[4], int lane, int bc, int bt) {
    if (bt < 6) {
        if (bc < 6) {
            bool ctrl = (lane >> bc) & 1;
#pragma unroll
            for (int r = 0; r < 4; ++r) {
                c32 p = shfl_xor_c(st[r], 1 << bt);
                st[r].x = ctrl ? p.x : st[r].x;
                st[r].y = ctrl ? p.y : st[r].y;
            }
        } else {
#pragma unroll
            for (int r = 0; r < 4; ++r) {
                if ((r >> (bc - 6)) & 1) st[r] = shfl_xor_c(st[r], 1 << bt);
            }
        }
    } else {
        if (bc < 6) {
            bool ctrl = (lane >> bc) & 1;
            if (bt == 6) { cswap(ctrl, st[0], st[1]); cswap(ctrl, st[2], st[3]); }
            else         { cswap(ctrl, st[0], st[2]); cswap(ctrl, st[1], st[3]); }
        } else {
            if (bc == 7 && bt == 6) { c32 t = st[2]; st[2] = st[3]; st[3] = t; }
            else if (bc == 6 && bt == 7) { c32 t = st[1]; st[1] = st[3]; st[3] = t; }
        }
    }
}
__global__ __launch_bounds__(256) void qsim_kernel(const float* __restrict__ x,
                                                   const float* __restrict__ theta,
                                                   float* __restrict__ out,
                                                   int batch) {
    __shared__ float rot[2 * 8 * 8];
    const int t = threadIdx.x;
    if (t < 16) {
        const int l = t >> 3, w = t & 7;
        const float phi = theta[(l * 8 + w) * 3 + 0];
        const float th  = theta[(l * 8 + w) * 3 + 1];
        const float om  = theta[(l * 8 + w) * 3 + 2];
        const float c = cosf(0.5f * th), s = sinf(0.5f * th);
        const float p = 0.5f * (phi + om), m = 0.5f * (phi - om);
        float* g = &rot[t * 8];
        g[0] = c * cosf(p);  g[1] = -c * sinf(p);
        g[2] = -s * cosf(m); g[3] = -s * sinf(m);
        g[4] = s * cosf(m);  g[5] = -s * sinf(m);
        g[6] = c * cosf(p);  g[7] = c * sinf(p);
    }
    __syncthreads();
    const int lane = t & 63;
    const int b = blockIdx.x * 4 + (t >> 6);
    if (b >= batch) return;
    float c8 = 0.f, s8 = 0.f;
    if (lane < 8) {
        const float xv = 0.5f * x[b * 8 + lane];
        c8 = cosf(xv); s8 = sinf(xv);
    }
    c32 st[4];
#pragma unroll
    for (int r = 0; r < 4; ++r) { st[r].x = 0.f; st[r].y = 0.f; }
    if (lane == 0) st[0].x = 1.f;
#pragma unroll
    for (int w = 0; w < 8; ++w) {
        const float c = __shfl(c8, w, 64);
        const float s = __shfl(s8, w, 64);
        apply_rx(st, lane, 7 - w, c, s);
    }
#pragma unroll
    for (int l = 0; l < 2; ++l) {
#pragma unroll
        for (int w = 0; w < 8; ++w) {
            const float* g = &rot[(l * 8 + w) * 8];
            c32 g00{g[0], g[1]}, g01{g[2], g[3]}, g10{g[4], g[5]}, g11{g[6], g[7]};
            apply_rot(st, lane, 7 - w, g00, g01, g10, g11);
        }
        const int rr = l + 1;
#pragma unroll
        for (int w = 0; w < 8; ++w) apply_cnot(st, lane, 7 - w, 7 - ((w + rr) & 7));
    }
    float v = st[0].x * st[0].x + st[0].y * st[0].y
            + st[1].x * st[1].x + st[1].y * st[1].y
            - st[2].x * st[2].x - st[2].y * st[2].y
            - st[3].x * st[3].x - st[3].y * st[3].y;
#pragma unroll
    for (int off = 32; off > 0; off >>= 1) v += __shfl_xor(v, off, 64);
    if (lane == 0) out[b] = (v + 1.f) * 0.5f;
}

// ============================================================================
extern "C" void kernel_launch(void* const* d_in, const int* in_sizes, int n_in,
                              void* d_out, int out_size, void* d_ws, size_t ws_size,
                              hipStream_t stream) {
    const float* x     = (const float*)d_in[0];
    const float* theta = (const float*)d_in[1];
    float* out = (float*)d_out;
    const int batch = in_sizes[0] / 8;

    if (ws_size >= (size_t)WS_FLOATS_NEEDED * 4 + 256 && (batch & 15) == 0) {
        float* ws = (float*)d_ws;
        k_sub<<<dim3(16), dim3(1024), 0, stream>>>(theta, ws);
        k_fin<<<dim3(1), dim3(1024), 0, stream>>>(theta, ws);
        const int ngroups = batch / 16;                    // 8192
        const int blocks = (ngroups + 3) / 4;              // 4 waves/block, 1 group/wave
        k_main4<<<dim3(blocks), dim3(256), 0, stream>>>(x, ws + OFF_AF, out, ngroups);
    } else {
        qsim_kernel<<<dim3((batch + 3) / 4), dim3(256), 0, stream>>>(x, theta, out, batch);
    }
}